// Round 7
// baseline (944.624 us; speedup 1.0000x reference)
//
#include <hip/hip_runtime.h>
#include <stdint.h>

// Problem constants (B=4,S=2048 -> T=8192 tokens). Inputs fp32, OUTPUT fp32.
#define T_TOK 8192
#define DDIM  2048
#define NEXP  8
#define FDIM  1024
#define CAP   25600   // 16384 assignments + 8*128 pad + 8192 shared rows
#define NT_M  200     // CAP/128 M-tiles (fixed grid; blocks beyond off[9] exit)
#define BK    64

typedef __bf16 bf16x8 __attribute__((ext_vector_type(8)));
typedef float  f32x4  __attribute__((ext_vector_type(4)));

typedef const __attribute__((address_space(1))) uint32_t* as1_u32;
typedef __attribute__((address_space(3))) uint32_t* as3_u32;

// async global->LDS, 16B/lane; LDS dest = wave-uniform base + lane*16 (linear)
__device__ __forceinline__ void gload16(const void* g, void* l) {
  __builtin_amdgcn_global_load_lds((as1_u32)g, (as3_u32)l, 16, 0, 0);
}

__device__ __forceinline__ float bf2f(uint16_t u) {
  union { uint32_t i; float f; } v; v.i = ((uint32_t)u) << 16; return v.f;
}
__device__ __forceinline__ uint16_t f2bf(float f) {
  union { float f; uint32_t i; } v; v.f = f;
  uint32_t i = v.i;
  i += 0x7FFFu + ((i >> 16) & 1u);   // RNE
  return (uint16_t)(i >> 16);
}

// ---------------------------------------------------------------------------
// K1: RMSNorm + router, all fp32. h stored as bf16 (MFMA operand).
// ---------------------------------------------------------------------------
__global__ __launch_bounds__(256) void k_rms_router(
    const float* __restrict__ x, const float* __restrict__ rmsw,
    const float* __restrict__ router_w, uint16_t* __restrict__ h,
    int* __restrict__ topi, float* __restrict__ topw, int* __restrict__ counts)
{
  int t = blockIdx.x, tid = threadIdx.x;
  int lane = tid & 63, wv = tid >> 6;
  const float* xr = x + (size_t)t * DDIM;
  float4 x0 = ((const float4*)xr)[tid * 2];
  float4 x1 = ((const float4*)xr)[tid * 2 + 1];
  float4 w0 = ((const float4*)rmsw)[tid * 2];
  float4 w1 = ((const float4*)rmsw)[tid * 2 + 1];
  float xv[8] = {x0.x, x0.y, x0.z, x0.w, x1.x, x1.y, x1.z, x1.w};
  float wv8[8] = {w0.x, w0.y, w0.z, w0.w, w1.x, w1.y, w1.z, w1.w};
  float ss = 0.f;
  #pragma unroll
  for (int j = 0; j < 8; j++) ss += xv[j] * xv[j];
  #pragma unroll
  for (int m = 32; m >= 1; m >>= 1) ss += __shfl_xor(ss, m, 64);
  __shared__ float rs[4];
  __shared__ float sscale;
  if (lane == 0) rs[wv] = ss;
  __syncthreads();
  if (tid == 0) sscale = rsqrtf((rs[0] + rs[1] + rs[2] + rs[3]) * (1.0f / DDIM) + 1e-6f);
  __syncthreads();
  float scale = sscale;
  float hv[8];
  #pragma unroll
  for (int j = 0; j < 8; j++) hv[j] = xv[j] * scale * wv8[j];
  ushort4 h0, h1;
  h0.x = f2bf(hv[0]); h0.y = f2bf(hv[1]); h0.z = f2bf(hv[2]); h0.w = f2bf(hv[3]);
  h1.x = f2bf(hv[4]); h1.y = f2bf(hv[5]); h1.z = f2bf(hv[6]); h1.w = f2bf(hv[7]);
  ((ushort4*)(h + (size_t)t * DDIM))[tid * 2]     = h0;
  ((ushort4*)(h + (size_t)t * DDIM))[tid * 2 + 1] = h1;

  float lp[8] = {0, 0, 0, 0, 0, 0, 0, 0};
  const float* rwm = router_w + (size_t)tid * 8 * NEXP;
  #pragma unroll
  for (int j = 0; j < 8; j++) {
    float4 a = ((const float4*)(rwm + j * NEXP))[0];
    float4 b = ((const float4*)(rwm + j * NEXP))[1];
    float hj = hv[j];
    lp[0] += hj * a.x; lp[1] += hj * a.y; lp[2] += hj * a.z; lp[3] += hj * a.w;
    lp[4] += hj * b.x; lp[5] += hj * b.y; lp[6] += hj * b.z; lp[7] += hj * b.w;
  }
  #pragma unroll
  for (int m = 32; m >= 1; m >>= 1) {
    #pragma unroll
    for (int e = 0; e < 8; e++) lp[e] += __shfl_xor(lp[e], m, 64);
  }
  __shared__ float rl[4][8];
  if (lane == 0) {
    #pragma unroll
    for (int e = 0; e < 8; e++) rl[wv][e] = lp[e];
  }
  __syncthreads();
  if (tid == 0) {
    float lg[8];
    #pragma unroll
    for (int e = 0; e < 8; e++) lg[e] = rl[0][e] + rl[1][e] + rl[2][e] + rl[3][e];
    int i0 = 0;
    for (int e = 1; e < 8; e++) if (lg[e] > lg[i0]) i0 = e;   // earliest max
    int i1 = (i0 == 0) ? 1 : 0;
    for (int e = 0; e < 8; e++) if (e != i0 && lg[e] > lg[i1]) i1 = e;
    float p0 = 1.f / (1.f + expf(lg[i1] - lg[i0]));  // renormalized top-2
    topi[t * 2] = i0; topi[t * 2 + 1] = i1;
    topw[t * 2] = p0; topw[t * 2 + 1] = 1.f - p0;
    atomicAdd(&counts[i0], 1);
    atomicAdd(&counts[i1], 1);
  }
}

// ---------------------------------------------------------------------------
__global__ void k_offsets(const int* __restrict__ counts, int* __restrict__ off) {
  if (threadIdx.x == 0 && blockIdx.x == 0) {
    int o = 0;
    for (int e = 0; e < NEXP; e++) { off[e] = o; o += (counts[e] + 127) & ~127; }
    off[8] = o;
    off[9] = o + T_TOK;
  }
}

// ---------------------------------------------------------------------------
__global__ __launch_bounds__(256) void k_scatter(
    const int* __restrict__ topi, const float* __restrict__ topw,
    const int* __restrict__ off, int* __restrict__ cursor,
    int* __restrict__ tokslot, float* __restrict__ wtrow)
{
  int idx = blockIdx.x * 256 + threadIdx.x;   // 0..24575
  if (idx < T_TOK * 2) {
    int t = idx >> 1, k = idx & 1;
    int e = topi[idx];
    int slot = atomicAdd(&cursor[e], 1);
    int row = off[e] + slot;
    tokslot[row] = t * 4 + k;
    wtrow[row] = topw[idx];
  } else {
    int t = idx - T_TOK * 2;
    int row = off[8] + t;
    tokslot[row] = t * 4 + 2;
    wtrow[row] = 1.0f;
  }
}

// ---------------------------------------------------------------------------
// K4: tiled convert-transpose fp32 [R][C] -> bf16 [C][R], batched over z.
// ---------------------------------------------------------------------------
__global__ __launch_bounds__(256) void k_transpose_cvt(
    const float* __restrict__ src, uint16_t* __restrict__ dst, int R, int C)
{
  __shared__ float tile[32][33];
  size_t mb = (size_t)blockIdx.z * R * C;
  int c0 = blockIdx.x * 32, r0 = blockIdx.y * 32;
  int tx = threadIdx.x & 31, ty = threadIdx.x >> 5;  // 32x8
  #pragma unroll
  for (int i = 0; i < 4; i++)
    tile[ty + 8 * i][tx] = src[mb + (size_t)(r0 + ty + 8 * i) * C + c0 + tx];
  __syncthreads();
  #pragma unroll
  for (int i = 0; i < 4; i++)
    dst[mb + (size_t)(c0 + ty + 8 * i) * R + r0 + tx] = f2bf(tile[tx][ty + 8 * i]);
}

// ---------------------------------------------------------------------------
// K5: stage-1 grouped GEMM, m97-style 128x128 tile via concat-B:
//   B rows 0..63 = W_gate cols f0..f0+63, rows 64..127 = W_up cols.
// global_load_lds w16 staging, linear LDS [128][64], 2 barriers/K-step.
// Epilogue: u-half exchanged through LDS (fp32), silu(g)*u -> bf16 A_int.
// ---------------------------------------------------------------------------
__global__ __launch_bounds__(256) void k_stage1(
    const uint16_t* __restrict__ h, const uint16_t* __restrict__ wgT,
    const uint16_t* __restrict__ wuT, const uint16_t* __restrict__ sgT,
    const uint16_t* __restrict__ suT, const int* __restrict__ off,
    const int* __restrict__ tokslot, uint16_t* __restrict__ A_int)
{
  __shared__ __align__(16) uint16_t sAB[2 * 128 * 64];  // 32 KB; reused as fp32 uBuf
  uint16_t* sA = sAB;
  uint16_t* sB = sAB + 128 * 64;

  int row0 = blockIdx.x * 128;
  int end = off[9];
  if (row0 >= end) return;
  int e = 0;
  #pragma unroll 1
  for (; e < 9; e++) if (row0 >= off[e] && row0 < off[e + 1]) break;
  const uint16_t* bg = (e < NEXP) ? wgT + (size_t)e * FDIM * DDIM : sgT;
  const uint16_t* bu = (e < NEXP) ? wuT + (size_t)e * FDIM * DDIM : suT;
  int f0 = blockIdx.y * 64;

  int tid = threadIdx.x, lane = tid & 63, w = tid >> 6;

  // staging sources: granule G = w*256 + i*64 + lane -> row r = w*32+i*8+(lane>>3),
  // 16B slot sl = lane&7. LDS dest linear at G*16 bytes.
  const uint16_t* srcA[4];
  const uint16_t* srcB[4];
  #pragma unroll
  for (int i = 0; i < 4; i++) {
    int r = w * 32 + i * 8 + (lane >> 3);
    int sl = lane & 7;
    int ts = tokslot[row0 + r];
    int tok = ts < 0 ? 0 : (ts >> 2);       // padded rows: token 0 (discarded)
    srcA[i] = h + (size_t)tok * DDIM + sl * 8;
    const uint16_t* bb = (r < 64) ? (bg + (size_t)(f0 + r) * DDIM)
                                  : (bu + (size_t)(f0 + r - 64) * DDIM);
    srcB[i] = bb + sl * 8;
  }

  f32x4 acc[4][4] = {};

  for (int kt = 0; kt < DDIM; kt += BK) {
    #pragma unroll
    for (int i = 0; i < 4; i++) {
      gload16(srcA[i] + kt, sA + (w * 256 + i * 64) * 8);
      gload16(srcB[i] + kt, sB + (w * 256 + i * 64) * 8);
    }
    __syncthreads();
    #pragma unroll
    for (int ks = 0; ks < 2; ks++) {
      int ce = ks * 32 + ((lane >> 4) << 3);   // element offset in K-tile
      bf16x8 av[4], bv[4];
      #pragma unroll
      for (int m = 0; m < 4; m++) {
        int rr = (w & 1) * 64 + m * 16 + (lane & 15);
        av[m] = *(const bf16x8*)(sA + rr * 64 + ce);
      }
      #pragma unroll
      for (int n = 0; n < 4; n++) {
        int rr = (w >> 1) * 64 + n * 16 + (lane & 15);
        bv[n] = *(const bf16x8*)(sB + rr * 64 + ce);
      }
      #pragma unroll
      for (int m = 0; m < 4; m++) {
        #pragma unroll
        for (int n = 0; n < 4; n++)
          acc[m][n] = __builtin_amdgcn_mfma_f32_16x16x32_bf16(av[m], bv[n], acc[m][n], 0, 0, 0);
      }
    }
    __syncthreads();
  }

  // epilogue: waves 2,3 hold the U-half -> stash fp32 in LDS; waves 0,1 hold G.
  float* uBuf = (float*)sAB;   // [128][64] fp32 = 32 KB (last barrier already passed)
  if (w >= 2) {
    #pragma unroll
    for (int m = 0; m < 4; m++) {
      #pragma unroll
      for (int n = 0; n < 4; n++) {
        #pragma unroll
        for (int r = 0; r < 4; r++) {
          int lrow = (w & 1) * 64 + m * 16 + ((lane >> 4) << 2) + r;
          int col = n * 16 + (lane & 15);
          uBuf[lrow * 64 + col] = acc[m][n][r];
        }
      }
    }
  }
  __syncthreads();
  if (w < 2) {
    #pragma unroll
    for (int m = 0; m < 4; m++) {
      #pragma unroll
      for (int n = 0; n < 4; n++) {
        #pragma unroll
        for (int r = 0; r < 4; r++) {
          int lrow = (w & 1) * 64 + m * 16 + ((lane >> 4) << 2) + r;
          int col = n * 16 + (lane & 15);
          float g = acc[m][n][r];
          float u = uBuf[lrow * 64 + col];
          float a = (g / (1.f + expf(-g))) * u;
          A_int[(size_t)(row0 + lrow) * FDIM + f0 + col] = f2bf(a);
        }
      }
    }
  }
}

// ---------------------------------------------------------------------------
// K6: stage-2 grouped GEMM: EO = A_int @ W_down. m97-style gload_lds staging.
// Routed rows: fp32*weight -> eo_r[tok][slot][*]. Shared rows: fp32 -> out.
// Block: 128 rows x 128 d-cols, BK=64, 4 waves (2x2) each 64x64.
// ---------------------------------------------------------------------------
__global__ __launch_bounds__(256) void k_stage2(
    const uint16_t* __restrict__ A_int, const uint16_t* __restrict__ wdT,
    const uint16_t* __restrict__ sdT, const int* __restrict__ off,
    const int* __restrict__ tokslot, const float* __restrict__ wtrow,
    float* __restrict__ eo_r, float* __restrict__ out)
{
  __shared__ __align__(16) uint16_t sA[128 * 64];
  __shared__ __align__(16) uint16_t sB[128 * 64];

  int row0 = blockIdx.x * 128;
  int end = off[9];
  if (row0 >= end) return;
  int e = 0;
  #pragma unroll 1
  for (; e < 9; e++) if (row0 >= off[e] && row0 < off[e + 1]) break;
  const uint16_t* bw = (e < NEXP) ? wdT + (size_t)e * DDIM * FDIM : sdT;
  int d0 = blockIdx.y * 128;

  int tid = threadIdx.x, lane = tid & 63, w = tid >> 6;

  const uint16_t* srcA[4];
  const uint16_t* srcB[4];
  #pragma unroll
  for (int i = 0; i < 4; i++) {
    int r = w * 32 + i * 8 + (lane >> 3);
    int sl = lane & 7;
    srcA[i] = A_int + (size_t)(row0 + r) * FDIM + sl * 8;
    srcB[i] = bw + (size_t)(d0 + r) * FDIM + sl * 8;
  }

  f32x4 acc[4][4] = {};

  for (int kt = 0; kt < FDIM; kt += BK) {
    #pragma unroll
    for (int i = 0; i < 4; i++) {
      gload16(srcA[i] + kt, sA + (w * 256 + i * 64) * 8);
      gload16(srcB[i] + kt, sB + (w * 256 + i * 64) * 8);
    }
    __syncthreads();
    #pragma unroll
    for (int ks = 0; ks < 2; ks++) {
      int ce = ks * 32 + ((lane >> 4) << 3);
      bf16x8 av[4], bv[4];
      #pragma unroll
      for (int m = 0; m < 4; m++) {
        int rr = (w & 1) * 64 + m * 16 + (lane & 15);
        av[m] = *(const bf16x8*)(sA + rr * 64 + ce);
      }
      #pragma unroll
      for (int n = 0; n < 4; n++) {
        int rr = (w >> 1) * 64 + n * 16 + (lane & 15);
        bv[n] = *(const bf16x8*)(sB + rr * 64 + ce);
      }
      #pragma unroll
      for (int m = 0; m < 4; m++) {
        #pragma unroll
        for (int n = 0; n < 4; n++)
          acc[m][n] = __builtin_amdgcn_mfma_f32_16x16x32_bf16(av[m], bv[n], acc[m][n], 0, 0, 0);
      }
    }
    __syncthreads();
  }

  int wr = (w & 1) * 64, wc = (w >> 1) * 64;
  #pragma unroll
  for (int m = 0; m < 4; m++) {
    #pragma unroll
    for (int r = 0; r < 4; r++) {
      int grow = row0 + wr + m * 16 + ((lane >> 4) << 2) + r;
      int ts = tokslot[grow];
      if (ts < 0) continue;                  // padded row
      int tok = ts >> 2, slot = ts & 3;
      if (slot == 2) {                       // shared expert -> fp32 out
        size_t obase = (size_t)tok * DDIM;
        #pragma unroll
        for (int n = 0; n < 4; n++) {
          int col = d0 + wc + n * 16 + (lane & 15);
          out[obase + col] = acc[m][n][r];
        }
      } else {                               // routed -> fp32 weighted slot
        float wt = wtrow[grow];
        size_t obase = ((size_t)tok * 2 + slot) * DDIM;
        #pragma unroll
        for (int n = 0; n < 4; n++) {
          int col = d0 + wc + n * 16 + (lane & 15);
          eo_r[obase + col] = acc[m][n][r] * wt;
        }
      }
    }
  }
}

// ---------------------------------------------------------------------------
// K7: out = out_shared + eo_r[slot0] + eo_r[slot1]   (all fp32)
// ---------------------------------------------------------------------------
__global__ __launch_bounds__(256) void k_final(
    const float* __restrict__ eo_r, float* __restrict__ out)
{
  int tok = blockIdx.x;
  int col = threadIdx.x * 8;
  const float* e0 = eo_r + ((size_t)tok * 2) * DDIM + col;
  const float* e1 = eo_r + ((size_t)tok * 2 + 1) * DDIM + col;
  float* op = out + (size_t)tok * DDIM + col;
  float4 s0 = *(const float4*)(op);
  float4 s1 = *(const float4*)(op + 4);
  float4 a0 = *(const float4*)(e0);
  float4 a1 = *(const float4*)(e0 + 4);
  float4 b0 = *(const float4*)(e1);
  float4 b1 = *(const float4*)(e1 + 4);
  float4 o0, o1;
  o0.x = s0.x + a0.x + b0.x;  o0.y = s0.y + a0.y + b0.y;
  o0.z = s0.z + a0.z + b0.z;  o0.w = s0.w + a0.w + b0.w;
  o1.x = s1.x + a1.x + b1.x;  o1.y = s1.y + a1.y + b1.y;
  o1.z = s1.z + a1.z + b1.z;  o1.w = s1.w + a1.w + b1.w;
  *(float4*)(op) = o0;
  *(float4*)(op + 4) = o1;
}

// ---------------------------------------------------------------------------
extern "C" void kernel_launch(void* const* d_in, const int* in_sizes, int n_in,
                              void* d_out, int out_size, void* d_ws, size_t ws_size,
                              hipStream_t stream) {
  (void)in_sizes; (void)n_in; (void)out_size;
  const float* x    = (const float*)d_in[0];
  const float* rmsw = (const float*)d_in[1];
  const float* rtw  = (const float*)d_in[2];
  const float* wg   = (const float*)d_in[3];
  const float* wu   = (const float*)d_in[4];
  const float* wd   = (const float*)d_in[5];
  const float* sg   = (const float*)d_in[6];
  const float* su   = (const float*)d_in[7];
  const float* sd   = (const float*)d_in[8];
  float* out = (float*)d_out;   // reference output dtype is float32

  // ---- workspace layout with lifetime overlays (224.73 MB, known to fit) ----
  char* base = (char*)d_ws;
  size_t off_b = 0;
  auto place = [&](size_t bytes) { size_t r = off_b; off_b += (bytes + 255) & ~(size_t)255; return r; };
  size_t o_topi    = place((size_t)T_TOK * 2 * 4);
  size_t o_topw    = place((size_t)T_TOK * 2 * 4);
  size_t o_counts  = place(64);
  size_t o_offs    = place(64);
  size_t o_cursor  = place(64);
  size_t o_tokslot = place((size_t)CAP * 4);
  size_t o_wtrow   = place((size_t)CAP * 4);
  // eo_r: fp32 [T][2][D] (phase C/D). Overlaid by h/wgT/wuT/sgT/suT (phase A/B).
  size_t o_eor = place((size_t)T_TOK * 2 * DDIM * 4);           // 134.22 MB
  size_t o_h   = o_eor;                                         // 33.55 MB
  size_t o_wgT = o_eor + (size_t)T_TOK * DDIM * 2;              // 33.55 MB
  size_t o_wuT = o_wgT + (size_t)NEXP * FDIM * DDIM * 2;        // 33.55 MB
  size_t o_sgT = o_wuT + (size_t)NEXP * FDIM * DDIM * 2;        // 4.19 MB
  size_t o_suT = o_sgT + (size_t)FDIM * DDIM * 2;               // 4.19 MB (ends 109.05 < 134.22)
  size_t o_wdT = place((size_t)NEXP * DDIM * FDIM * 2);         // 33.55 MB
  size_t o_sdT = place((size_t)DDIM * FDIM * 2);                // 4.19 MB
  size_t o_Ai  = place((size_t)CAP * FDIM * 2);                 // 52.43 MB
  size_t NEED = off_b;
  if (ws_size < NEED) return;  // clean diagnostic instead of fault

  int*      topi    = (int*)(base + o_topi);
  float*    topw    = (float*)(base + o_topw);
  int*      counts  = (int*)(base + o_counts);
  int*      offs    = (int*)(base + o_offs);
  int*      cursor  = (int*)(base + o_cursor);
  int*      tokslot = (int*)(base + o_tokslot);
  float*    wtrow   = (float*)(base + o_wtrow);
  float*    eo_r    = (float*)(base + o_eor);
  uint16_t* h       = (uint16_t*)(base + o_h);
  uint16_t* wgT     = (uint16_t*)(base + o_wgT);
  uint16_t* wuT     = (uint16_t*)(base + o_wuT);
  uint16_t* sgT     = (uint16_t*)(base + o_sgT);
  uint16_t* suT     = (uint16_t*)(base + o_suT);
  uint16_t* wdT     = (uint16_t*)(base + o_wdT);
  uint16_t* sdT     = (uint16_t*)(base + o_sdT);
  uint16_t* Ai      = (uint16_t*)(base + o_Ai);

  hipMemsetAsync(counts, 0, 64, stream);
  hipMemsetAsync(cursor, 0, 64, stream);
  hipMemsetAsync(tokslot, 0xFF, (size_t)CAP * 4, stream);  // -1 = padded row

  // fp32 -> bf16 convert-transposes ([d][f] -> [f][d] etc.)
  k_transpose_cvt<<<dim3(FDIM / 32, DDIM / 32, NEXP), 256, 0, stream>>>(wg, wgT, DDIM, FDIM);
  k_transpose_cvt<<<dim3(FDIM / 32, DDIM / 32, NEXP), 256, 0, stream>>>(wu, wuT, DDIM, FDIM);
  k_transpose_cvt<<<dim3(DDIM / 32, FDIM / 32, NEXP), 256, 0, stream>>>(wd, wdT, FDIM, DDIM);
  k_transpose_cvt<<<dim3(FDIM / 32, DDIM / 32, 1),    256, 0, stream>>>(sg, sgT, DDIM, FDIM);
  k_transpose_cvt<<<dim3(FDIM / 32, DDIM / 32, 1),    256, 0, stream>>>(su, suT, DDIM, FDIM);
  k_transpose_cvt<<<dim3(DDIM / 32, FDIM / 32, 1),    256, 0, stream>>>(sd, sdT, FDIM, DDIM);

  k_rms_router<<<T_TOK, 256, 0, stream>>>(x, rmsw, rtw, h, topi, topw, counts);
  k_offsets<<<1, 64, 0, stream>>>(counts, offs);
  k_scatter<<<(T_TOK * 3) / 256, 256, 0, stream>>>(topi, topw, offs, cursor, tokslot, wtrow);

  k_stage1<<<dim3(NT_M, FDIM / 64), 256, 0, stream>>>(h, wgT, wuT, sgT, suT, offs, tokslot, Ai);
  // stage2 overwrites the h/wgT/wuT/sgT/suT region (now dead) as eo_r
  k_stage2<<<dim3(NT_M, DDIM / 128), 256, 0, stream>>>(Ai, wdT, sdT, offs, tokslot, wtrow, eo_r, out);
  k_final<<<T_TOK, 256, 0, stream>>>(eo_r, out);
}

// Round 8
// 876.234 us; speedup vs baseline: 1.0780x; 1.0780x over previous
//
#include <hip/hip_runtime.h>
#include <stdint.h>

// Problem constants (B=4,S=2048 -> T=8192 tokens). Inputs fp32, OUTPUT fp32.
#define T_TOK 8192
#define DDIM  2048
#define NEXP  8
#define FDIM  1024
#define CAP   25600   // 16384 assignments + 8*128 pad + 8192 shared rows
#define NT_M  200     // CAP/128 M-tiles (fixed grid; blocks beyond off[9] exit)
#define BK    64

typedef __bf16 bf16x8 __attribute__((ext_vector_type(8)));
typedef float  f32x4  __attribute__((ext_vector_type(4)));

typedef const __attribute__((address_space(1))) uint32_t* as1_u32;
typedef __attribute__((address_space(3))) uint32_t* as3_u32;

// async global->LDS, 16B/lane; LDS dest = wave-uniform base + lane*16 (linear)
__device__ __forceinline__ void gload16(const void* g, void* l) {
  __builtin_amdgcn_global_load_lds((as1_u32)g, (as3_u32)l, 16, 0, 0);
}

__device__ __forceinline__ float bf2f(uint16_t u) {
  union { uint32_t i; float f; } v; v.i = ((uint32_t)u) << 16; return v.f;
}
__device__ __forceinline__ uint16_t f2bf(float f) {
  union { float f; uint32_t i; } v; v.f = f;
  uint32_t i = v.i;
  i += 0x7FFFu + ((i >> 16) & 1u);   // RNE
  return (uint16_t)(i >> 16);
}

// ---------------------------------------------------------------------------
// K1: RMSNorm + router, all fp32. h stored as bf16 (MFMA operand).
// ---------------------------------------------------------------------------
__global__ __launch_bounds__(256) void k_rms_router(
    const float* __restrict__ x, const float* __restrict__ rmsw,
    const float* __restrict__ router_w, uint16_t* __restrict__ h,
    int* __restrict__ topi, float* __restrict__ topw, int* __restrict__ counts)
{
  int t = blockIdx.x, tid = threadIdx.x;
  int lane = tid & 63, wv = tid >> 6;
  const float* xr = x + (size_t)t * DDIM;
  float4 x0 = ((const float4*)xr)[tid * 2];
  float4 x1 = ((const float4*)xr)[tid * 2 + 1];
  float4 w0 = ((const float4*)rmsw)[tid * 2];
  float4 w1 = ((const float4*)rmsw)[tid * 2 + 1];
  float xv[8] = {x0.x, x0.y, x0.z, x0.w, x1.x, x1.y, x1.z, x1.w};
  float wv8[8] = {w0.x, w0.y, w0.z, w0.w, w1.x, w1.y, w1.z, w1.w};
  float ss = 0.f;
  #pragma unroll
  for (int j = 0; j < 8; j++) ss += xv[j] * xv[j];
  #pragma unroll
  for (int m = 32; m >= 1; m >>= 1) ss += __shfl_xor(ss, m, 64);
  __shared__ float rs[4];
  __shared__ float sscale;
  if (lane == 0) rs[wv] = ss;
  __syncthreads();
  if (tid == 0) sscale = rsqrtf((rs[0] + rs[1] + rs[2] + rs[3]) * (1.0f / DDIM) + 1e-6f);
  __syncthreads();
  float scale = sscale;
  float hv[8];
  #pragma unroll
  for (int j = 0; j < 8; j++) hv[j] = xv[j] * scale * wv8[j];
  ushort4 h0, h1;
  h0.x = f2bf(hv[0]); h0.y = f2bf(hv[1]); h0.z = f2bf(hv[2]); h0.w = f2bf(hv[3]);
  h1.x = f2bf(hv[4]); h1.y = f2bf(hv[5]); h1.z = f2bf(hv[6]); h1.w = f2bf(hv[7]);
  ((ushort4*)(h + (size_t)t * DDIM))[tid * 2]     = h0;
  ((ushort4*)(h + (size_t)t * DDIM))[tid * 2 + 1] = h1;

  float lp[8] = {0, 0, 0, 0, 0, 0, 0, 0};
  const float* rwm = router_w + (size_t)tid * 8 * NEXP;
  #pragma unroll
  for (int j = 0; j < 8; j++) {
    float4 a = ((const float4*)(rwm + j * NEXP))[0];
    float4 b = ((const float4*)(rwm + j * NEXP))[1];
    float hj = hv[j];
    lp[0] += hj * a.x; lp[1] += hj * a.y; lp[2] += hj * a.z; lp[3] += hj * a.w;
    lp[4] += hj * b.x; lp[5] += hj * b.y; lp[6] += hj * b.z; lp[7] += hj * b.w;
  }
  #pragma unroll
  for (int m = 32; m >= 1; m >>= 1) {
    #pragma unroll
    for (int e = 0; e < 8; e++) lp[e] += __shfl_xor(lp[e], m, 64);
  }
  __shared__ float rl[4][8];
  if (lane == 0) {
    #pragma unroll
    for (int e = 0; e < 8; e++) rl[wv][e] = lp[e];
  }
  __syncthreads();
  if (tid == 0) {
    float lg[8];
    #pragma unroll
    for (int e = 0; e < 8; e++) lg[e] = rl[0][e] + rl[1][e] + rl[2][e] + rl[3][e];
    int i0 = 0;
    for (int e = 1; e < 8; e++) if (lg[e] > lg[i0]) i0 = e;   // earliest max
    int i1 = (i0 == 0) ? 1 : 0;
    for (int e = 0; e < 8; e++) if (e != i0 && lg[e] > lg[i1]) i1 = e;
    float p0 = 1.f / (1.f + expf(lg[i1] - lg[i0]));  // renormalized top-2
    topi[t * 2] = i0; topi[t * 2 + 1] = i1;
    topw[t * 2] = p0; topw[t * 2 + 1] = 1.f - p0;
    atomicAdd(&counts[i0], 1);
    atomicAdd(&counts[i1], 1);
  }
}

// ---------------------------------------------------------------------------
__global__ void k_offsets(const int* __restrict__ counts, int* __restrict__ off) {
  if (threadIdx.x == 0 && blockIdx.x == 0) {
    int o = 0;
    for (int e = 0; e < NEXP; e++) { off[e] = o; o += (counts[e] + 127) & ~127; }
    off[8] = o;
    off[9] = o + T_TOK;
  }
}

// ---------------------------------------------------------------------------
__global__ __launch_bounds__(256) void k_scatter(
    const int* __restrict__ topi, const float* __restrict__ topw,
    const int* __restrict__ off, int* __restrict__ cursor,
    int* __restrict__ tokslot, float* __restrict__ wtrow)
{
  int idx = blockIdx.x * 256 + threadIdx.x;   // 0..24575
  if (idx < T_TOK * 2) {
    int t = idx >> 1, k = idx & 1;
    int e = topi[idx];
    int slot = atomicAdd(&cursor[e], 1);
    int row = off[e] + slot;
    tokslot[row] = t * 4 + k;
    wtrow[row] = topw[idx];
  } else {
    int t = idx - T_TOK * 2;
    int row = off[8] + t;
    tokslot[row] = t * 4 + 2;
    wtrow[row] = 1.0f;
  }
}

// ---------------------------------------------------------------------------
// K4a: batched convert-transpose for D->F weights ([2048][1024] -> [1024][2048]):
//   z 0..7 = wg experts, 8..15 = wu experts, 16 = sg, 17 = su.
// ---------------------------------------------------------------------------
__global__ __launch_bounds__(256) void k_tr_df(
    const float* __restrict__ wg, const float* __restrict__ wu,
    const float* __restrict__ sg, const float* __restrict__ su,
    uint16_t* __restrict__ wgT, uint16_t* __restrict__ wuT,
    uint16_t* __restrict__ sgT, uint16_t* __restrict__ suT)
{
  __shared__ float tile[32][33];
  int z = blockIdx.z;
  const float* src; uint16_t* dst;
  if (z < 8)       { src = wg + (size_t)z * DDIM * FDIM;       dst = wgT + (size_t)z * FDIM * DDIM; }
  else if (z < 16) { src = wu + (size_t)(z - 8) * DDIM * FDIM; dst = wuT + (size_t)(z - 8) * FDIM * DDIM; }
  else if (z == 16){ src = sg; dst = sgT; }
  else             { src = su; dst = suT; }
  int c0 = blockIdx.x * 32, r0 = blockIdx.y * 32;
  int tx = threadIdx.x & 31, ty = threadIdx.x >> 5;  // 32x8
  #pragma unroll
  for (int i = 0; i < 4; i++)
    tile[ty + 8 * i][tx] = src[(size_t)(r0 + ty + 8 * i) * FDIM + c0 + tx];
  __syncthreads();
  #pragma unroll
  for (int i = 0; i < 4; i++)
    dst[(size_t)(c0 + ty + 8 * i) * DDIM + r0 + tx] = f2bf(tile[tx][ty + 8 * i]);
}

// K4b: batched convert-transpose for F->D weights ([1024][2048] -> [2048][1024]):
//   z 0..7 = wd experts, 8 = sd.
__global__ __launch_bounds__(256) void k_tr_fd(
    const float* __restrict__ wd, const float* __restrict__ sd,
    uint16_t* __restrict__ wdT, uint16_t* __restrict__ sdT)
{
  __shared__ float tile[32][33];
  int z = blockIdx.z;
  const float* src; uint16_t* dst;
  if (z < 8) { src = wd + (size_t)z * FDIM * DDIM; dst = wdT + (size_t)z * DDIM * FDIM; }
  else       { src = sd; dst = sdT; }
  int c0 = blockIdx.x * 32, r0 = blockIdx.y * 32;
  int tx = threadIdx.x & 31, ty = threadIdx.x >> 5;  // 32x8
  #pragma unroll
  for (int i = 0; i < 4; i++)
    tile[ty + 8 * i][tx] = src[(size_t)(r0 + ty + 8 * i) * DDIM + c0 + tx];
  __syncthreads();
  #pragma unroll
  for (int i = 0; i < 4; i++)
    dst[(size_t)(c0 + ty + 8 * i) * FDIM + r0 + tx] = f2bf(tile[tx][ty + 8 * i]);
}

// ---------------------------------------------------------------------------
// K5: stage-1 grouped GEMM, 128x128 tile via concat-B (rows 0..63 = W_gate,
// 64..127 = W_up). gload_lds w16 staging with PRE-SWIZZLED source granule
// (gl = sl ^ (r&7)) -> linear LDS; ds_read applies matching XOR. (T2, rule #21)
// ---------------------------------------------------------------------------
__global__ __launch_bounds__(256) void k_stage1(
    const uint16_t* __restrict__ h, const uint16_t* __restrict__ wgT,
    const uint16_t* __restrict__ wuT, const uint16_t* __restrict__ sgT,
    const uint16_t* __restrict__ suT, const int* __restrict__ off,
    const int* __restrict__ tokslot, uint16_t* __restrict__ A_int)
{
  __shared__ __align__(16) uint16_t sAB[2 * 128 * 64];  // 32 KB; reused as fp32 uBuf
  uint16_t* sA = sAB;
  uint16_t* sB = sAB + 128 * 64;

  int row0 = blockIdx.x * 128;
  int end = off[9];
  if (row0 >= end) return;
  int e = 0;
  #pragma unroll 1
  for (; e < 9; e++) if (row0 >= off[e] && row0 < off[e + 1]) break;
  const uint16_t* bg = (e < NEXP) ? wgT + (size_t)e * FDIM * DDIM : sgT;
  const uint16_t* bu = (e < NEXP) ? wuT + (size_t)e * FDIM * DDIM : suT;
  int f0 = blockIdx.y * 64;

  int tid = threadIdx.x, lane = tid & 63, w = tid >> 6;

  // staging: granule G = w*256+i*64+lane -> LDS row r=G>>3, phys slot sl=G&7.
  // source granule gl = sl ^ (r&7) (pre-swizzle so read-side XOR restores).
  const uint16_t* srcA[4];
  const uint16_t* srcB[4];
  #pragma unroll
  for (int i = 0; i < 4; i++) {
    int r = w * 32 + i * 8 + (lane >> 3);
    int sl = lane & 7;
    int gl = sl ^ (r & 7);
    int ts = tokslot[row0 + r];
    int tok = ts < 0 ? 0 : (ts >> 2);       // padded rows: token 0 (discarded)
    srcA[i] = h + (size_t)tok * DDIM + gl * 8;
    const uint16_t* bb = (r < 64) ? (bg + (size_t)(f0 + r) * DDIM)
                                  : (bu + (size_t)(f0 + r - 64) * DDIM);
    srcB[i] = bb + gl * 8;
  }

  f32x4 acc[4][4] = {};

  for (int kt = 0; kt < DDIM; kt += BK) {
    #pragma unroll
    for (int i = 0; i < 4; i++) {
      gload16(srcA[i] + kt, sA + (w * 256 + i * 64) * 8);
      gload16(srcB[i] + kt, sB + (w * 256 + i * 64) * 8);
    }
    __syncthreads();
    #pragma unroll
    for (int ks = 0; ks < 2; ks++) {
      int ce = ks * 32 + ((lane >> 4) << 3);   // logical element offset in K-tile
      bf16x8 av[4], bv[4];
      #pragma unroll
      for (int m = 0; m < 4; m++) {
        int rr = (w & 1) * 64 + m * 16 + (lane & 15);
        av[m] = *(const bf16x8*)(sA + rr * 64 + (ce ^ ((rr & 7) << 3)));
      }
      #pragma unroll
      for (int n = 0; n < 4; n++) {
        int rr = (w >> 1) * 64 + n * 16 + (lane & 15);
        bv[n] = *(const bf16x8*)(sB + rr * 64 + (ce ^ ((rr & 7) << 3)));
      }
      #pragma unroll
      for (int m = 0; m < 4; m++) {
        #pragma unroll
        for (int n = 0; n < 4; n++)
          acc[m][n] = __builtin_amdgcn_mfma_f32_16x16x32_bf16(av[m], bv[n], acc[m][n], 0, 0, 0);
      }
    }
    __syncthreads();
  }

  // epilogue: waves 2,3 hold the U-half -> stash fp32 in LDS; waves 0,1 hold G.
  float* uBuf = (float*)sAB;   // [128][64] fp32 = 32 KB
  if (w >= 2) {
    #pragma unroll
    for (int m = 0; m < 4; m++) {
      #pragma unroll
      for (int n = 0; n < 4; n++) {
        #pragma unroll
        for (int r = 0; r < 4; r++) {
          int lrow = (w & 1) * 64 + m * 16 + ((lane >> 4) << 2) + r;
          int col = n * 16 + (lane & 15);
          uBuf[lrow * 64 + col] = acc[m][n][r];
        }
      }
    }
  }
  __syncthreads();
  if (w < 2) {
    #pragma unroll
    for (int m = 0; m < 4; m++) {
      #pragma unroll
      for (int n = 0; n < 4; n++) {
        #pragma unroll
        for (int r = 0; r < 4; r++) {
          int lrow = (w & 1) * 64 + m * 16 + ((lane >> 4) << 2) + r;
          int col = n * 16 + (lane & 15);
          float g = acc[m][n][r];
          float u = uBuf[lrow * 64 + col];
          float a = (g / (1.f + expf(-g))) * u;
          A_int[(size_t)(row0 + lrow) * FDIM + f0 + col] = f2bf(a);
        }
      }
    }
  }
}

// ---------------------------------------------------------------------------
// K6: stage-2 grouped GEMM: EO = A_int @ W_down. Same T2-swizzled staging.
// Routed rows: fp32*weight -> eo_r[tok][slot][*]. Shared rows: fp32 -> out.
// ---------------------------------------------------------------------------
__global__ __launch_bounds__(256) void k_stage2(
    const uint16_t* __restrict__ A_int, const uint16_t* __restrict__ wdT,
    const uint16_t* __restrict__ sdT, const int* __restrict__ off,
    const int* __restrict__ tokslot, const float* __restrict__ wtrow,
    float* __restrict__ eo_r, float* __restrict__ out)
{
  __shared__ __align__(16) uint16_t sA[128 * 64];
  __shared__ __align__(16) uint16_t sB[128 * 64];

  int row0 = blockIdx.x * 128;
  int end = off[9];
  if (row0 >= end) return;
  int e = 0;
  #pragma unroll 1
  for (; e < 9; e++) if (row0 >= off[e] && row0 < off[e + 1]) break;
  const uint16_t* bw = (e < NEXP) ? wdT + (size_t)e * DDIM * FDIM : sdT;
  int d0 = blockIdx.y * 128;

  int tid = threadIdx.x, lane = tid & 63, w = tid >> 6;

  const uint16_t* srcA[4];
  const uint16_t* srcB[4];
  #pragma unroll
  for (int i = 0; i < 4; i++) {
    int r = w * 32 + i * 8 + (lane >> 3);
    int sl = lane & 7;
    int gl = sl ^ (r & 7);
    srcA[i] = A_int + (size_t)(row0 + r) * FDIM + gl * 8;
    srcB[i] = bw + (size_t)(d0 + r) * FDIM + gl * 8;
  }

  f32x4 acc[4][4] = {};

  for (int kt = 0; kt < FDIM; kt += BK) {
    #pragma unroll
    for (int i = 0; i < 4; i++) {
      gload16(srcA[i] + kt, sA + (w * 256 + i * 64) * 8);
      gload16(srcB[i] + kt, sB + (w * 256 + i * 64) * 8);
    }
    __syncthreads();
    #pragma unroll
    for (int ks = 0; ks < 2; ks++) {
      int ce = ks * 32 + ((lane >> 4) << 3);
      bf16x8 av[4], bv[4];
      #pragma unroll
      for (int m = 0; m < 4; m++) {
        int rr = (w & 1) * 64 + m * 16 + (lane & 15);
        av[m] = *(const bf16x8*)(sA + rr * 64 + (ce ^ ((rr & 7) << 3)));
      }
      #pragma unroll
      for (int n = 0; n < 4; n++) {
        int rr = (w >> 1) * 64 + n * 16 + (lane & 15);
        bv[n] = *(const bf16x8*)(sB + rr * 64 + (ce ^ ((rr & 7) << 3)));
      }
      #pragma unroll
      for (int m = 0; m < 4; m++) {
        #pragma unroll
        for (int n = 0; n < 4; n++)
          acc[m][n] = __builtin_amdgcn_mfma_f32_16x16x32_bf16(av[m], bv[n], acc[m][n], 0, 0, 0);
      }
    }
    __syncthreads();
  }

  int wr = (w & 1) * 64, wc = (w >> 1) * 64;
  #pragma unroll
  for (int m = 0; m < 4; m++) {
    #pragma unroll
    for (int r = 0; r < 4; r++) {
      int grow = row0 + wr + m * 16 + ((lane >> 4) << 2) + r;
      int ts = tokslot[grow];
      if (ts < 0) continue;                  // padded row
      int tok = ts >> 2, slot = ts & 3;
      if (slot == 2) {                       // shared expert -> fp32 out
        size_t obase = (size_t)tok * DDIM;
        #pragma unroll
        for (int n = 0; n < 4; n++) {
          int col = d0 + wc + n * 16 + (lane & 15);
          out[obase + col] = acc[m][n][r];
        }
      } else {                               // routed -> fp32 weighted slot
        float wt = wtrow[grow];
        size_t obase = ((size_t)tok * 2 + slot) * DDIM;
        #pragma unroll
        for (int n = 0; n < 4; n++) {
          int col = d0 + wc + n * 16 + (lane & 15);
          eo_r[obase + col] = acc[m][n][r] * wt;
        }
      }
    }
  }
}

// ---------------------------------------------------------------------------
// K7: out = out_shared + eo_r[slot0] + eo_r[slot1]   (all fp32)
// ---------------------------------------------------------------------------
__global__ __launch_bounds__(256) void k_final(
    const float* __restrict__ eo_r, float* __restrict__ out)
{
  int tok = blockIdx.x;
  int col = threadIdx.x * 8;
  const float* e0 = eo_r + ((size_t)tok * 2) * DDIM + col;
  const float* e1 = eo_r + ((size_t)tok * 2 + 1) * DDIM + col;
  float* op = out + (size_t)tok * DDIM + col;
  float4 s0 = *(const float4*)(op);
  float4 s1 = *(const float4*)(op + 4);
  float4 a0 = *(const float4*)(e0);
  float4 a1 = *(const float4*)(e0 + 4);
  float4 b0 = *(const float4*)(e1);
  float4 b1 = *(const float4*)(e1 + 4);
  float4 o0, o1;
  o0.x = s0.x + a0.x + b0.x;  o0.y = s0.y + a0.y + b0.y;
  o0.z = s0.z + a0.z + b0.z;  o0.w = s0.w + a0.w + b0.w;
  o1.x = s1.x + a1.x + b1.x;  o1.y = s1.y + a1.y + b1.y;
  o1.z = s1.z + a1.z + b1.z;  o1.w = s1.w + a1.w + b1.w;
  *(float4*)(op) = o0;
  *(float4*)(op + 4) = o1;
}

// ---------------------------------------------------------------------------
extern "C" void kernel_launch(void* const* d_in, const int* in_sizes, int n_in,
                              void* d_out, int out_size, void* d_ws, size_t ws_size,
                              hipStream_t stream) {
  (void)in_sizes; (void)n_in; (void)out_size;
  const float* x    = (const float*)d_in[0];
  const float* rmsw = (const float*)d_in[1];
  const float* rtw  = (const float*)d_in[2];
  const float* wg   = (const float*)d_in[3];
  const float* wu   = (const float*)d_in[4];
  const float* wd   = (const float*)d_in[5];
  const float* sg   = (const float*)d_in[6];
  const float* su   = (const float*)d_in[7];
  const float* sd   = (const float*)d_in[8];
  float* out = (float*)d_out;   // reference output dtype is float32

  // ---- workspace layout with lifetime overlays (224.73 MB, known to fit) ----
  char* base = (char*)d_ws;
  size_t off_b = 0;
  auto place = [&](size_t bytes) { size_t r = off_b; off_b += (bytes + 255) & ~(size_t)255; return r; };
  size_t o_topi    = place((size_t)T_TOK * 2 * 4);
  size_t o_topw    = place((size_t)T_TOK * 2 * 4);
  size_t o_counts  = place(64);
  size_t o_offs    = place(64);
  size_t o_cursor  = place(64);
  size_t o_tokslot = place((size_t)CAP * 4);
  size_t o_wtrow   = place((size_t)CAP * 4);
  // eo_r: fp32 [T][2][D] (phase C/D). Overlaid by h/wgT/wuT/sgT/suT (phase A/B).
  size_t o_eor = place((size_t)T_TOK * 2 * DDIM * 4);           // 134.22 MB
  size_t o_h   = o_eor;                                         // 33.55 MB
  size_t o_wgT = o_eor + (size_t)T_TOK * DDIM * 2;              // 33.55 MB
  size_t o_wuT = o_wgT + (size_t)NEXP * FDIM * DDIM * 2;        // 33.55 MB
  size_t o_sgT = o_wuT + (size_t)NEXP * FDIM * DDIM * 2;        // 4.19 MB
  size_t o_suT = o_sgT + (size_t)FDIM * DDIM * 2;               // 4.19 MB (ends 109.05 < 134.22)
  size_t o_wdT = place((size_t)NEXP * DDIM * FDIM * 2);         // 33.55 MB
  size_t o_sdT = place((size_t)DDIM * FDIM * 2);                // 4.19 MB
  size_t o_Ai  = place((size_t)CAP * FDIM * 2);                 // 52.43 MB
  size_t NEED = off_b;
  if (ws_size < NEED) return;  // clean diagnostic instead of fault

  int*      topi    = (int*)(base + o_topi);
  float*    topw    = (float*)(base + o_topw);
  int*      counts  = (int*)(base + o_counts);
  int*      offs    = (int*)(base + o_offs);
  int*      cursor  = (int*)(base + o_cursor);
  int*      tokslot = (int*)(base + o_tokslot);
  float*    wtrow   = (float*)(base + o_wtrow);
  float*    eo_r    = (float*)(base + o_eor);
  uint16_t* h       = (uint16_t*)(base + o_h);
  uint16_t* wgT     = (uint16_t*)(base + o_wgT);
  uint16_t* wuT     = (uint16_t*)(base + o_wuT);
  uint16_t* sgT     = (uint16_t*)(base + o_sgT);
  uint16_t* suT     = (uint16_t*)(base + o_suT);
  uint16_t* wdT     = (uint16_t*)(base + o_wdT);
  uint16_t* sdT     = (uint16_t*)(base + o_sdT);
  uint16_t* Ai      = (uint16_t*)(base + o_Ai);

  hipMemsetAsync(counts, 0, 64, stream);
  hipMemsetAsync(cursor, 0, 64, stream);
  hipMemsetAsync(tokslot, 0xFF, (size_t)CAP * 4, stream);  // -1 = padded row

  // batched fp32 -> bf16 convert-transposes (2 launches instead of 6)
  k_tr_df<<<dim3(FDIM / 32, DDIM / 32, 18), 256, 0, stream>>>(wg, wu, sg, su, wgT, wuT, sgT, suT);
  k_tr_fd<<<dim3(DDIM / 32, FDIM / 32, 9),  256, 0, stream>>>(wd, sd, wdT, sdT);

  k_rms_router<<<T_TOK, 256, 0, stream>>>(x, rmsw, rtw, h, topi, topw, counts);
  k_offsets<<<1, 64, 0, stream>>>(counts, offs);
  k_scatter<<<(T_TOK * 3) / 256, 256, 0, stream>>>(topi, topw, offs, cursor, tokslot, wtrow);

  k_stage1<<<dim3(NT_M, FDIM / 64), 256, 0, stream>>>(h, wgT, wuT, sgT, suT, offs, tokslot, Ai);
  // stage2 overwrites the h/wgT/wuT/sgT/suT region (now dead) as eo_r
  k_stage2<<<dim3(NT_M, DDIM / 128), 256, 0, stream>>>(Ai, wdT, sdT, offs, tokslot, wtrow, eo_r, out);
  k_final<<<T_TOK, 256, 0, stream>>>(eo_r, out);
}

// Round 9
// 867.437 us; speedup vs baseline: 1.0890x; 1.0101x over previous
//
#include <hip/hip_runtime.h>
#include <stdint.h>

// Problem constants (B=4,S=2048 -> T=8192 tokens). Inputs fp32, OUTPUT fp32.
#define T_TOK 8192
#define DDIM  2048
#define NEXP  8
#define FDIM  1024
#define CAP   25600   // 16384 assignments + 8*128 pad + 8192 shared rows
#define NT_M  200     // CAP/128 M-tiles (fixed grid; blocks beyond off[9] exit)
#define BK    64

typedef __bf16 bf16x8 __attribute__((ext_vector_type(8)));
typedef float  f32x4  __attribute__((ext_vector_type(4)));

typedef const __attribute__((address_space(1))) uint32_t* as1_u32;
typedef __attribute__((address_space(3))) uint32_t* as3_u32;

// async global->LDS, 16B/lane; LDS dest = wave-uniform base + lane*16 (linear)
__device__ __forceinline__ void gload16(const void* g, void* l) {
  __builtin_amdgcn_global_load_lds((as1_u32)g, (as3_u32)l, 16, 0, 0);
}

__device__ __forceinline__ float bf2f(uint16_t u) {
  union { uint32_t i; float f; } v; v.i = ((uint32_t)u) << 16; return v.f;
}
__device__ __forceinline__ uint16_t f2bf(float f) {
  union { float f; uint32_t i; } v; v.f = f;
  uint32_t i = v.i;
  i += 0x7FFFu + ((i >> 16) & 1u);   // RNE
  return (uint16_t)(i >> 16);
}

// ---------------------------------------------------------------------------
// K1: RMSNorm + router, all fp32. h stored as bf16 (MFMA operand).
// ---------------------------------------------------------------------------
__global__ __launch_bounds__(256) void k_rms_router(
    const float* __restrict__ x, const float* __restrict__ rmsw,
    const float* __restrict__ router_w, uint16_t* __restrict__ h,
    int* __restrict__ topi, float* __restrict__ topw, int* __restrict__ counts)
{
  int t = blockIdx.x, tid = threadIdx.x;
  int lane = tid & 63, wv = tid >> 6;
  const float* xr = x + (size_t)t * DDIM;
  float4 x0 = ((const float4*)xr)[tid * 2];
  float4 x1 = ((const float4*)xr)[tid * 2 + 1];
  float4 w0 = ((const float4*)rmsw)[tid * 2];
  float4 w1 = ((const float4*)rmsw)[tid * 2 + 1];
  float xv[8] = {x0.x, x0.y, x0.z, x0.w, x1.x, x1.y, x1.z, x1.w};
  float wv8[8] = {w0.x, w0.y, w0.z, w0.w, w1.x, w1.y, w1.z, w1.w};
  float ss = 0.f;
  #pragma unroll
  for (int j = 0; j < 8; j++) ss += xv[j] * xv[j];
  #pragma unroll
  for (int m = 32; m >= 1; m >>= 1) ss += __shfl_xor(ss, m, 64);
  __shared__ float rs[4];
  __shared__ float sscale;
  if (lane == 0) rs[wv] = ss;
  __syncthreads();
  if (tid == 0) sscale = rsqrtf((rs[0] + rs[1] + rs[2] + rs[3]) * (1.0f / DDIM) + 1e-6f);
  __syncthreads();
  float scale = sscale;
  float hv[8];
  #pragma unroll
  for (int j = 0; j < 8; j++) hv[j] = xv[j] * scale * wv8[j];
  ushort4 h0, h1;
  h0.x = f2bf(hv[0]); h0.y = f2bf(hv[1]); h0.z = f2bf(hv[2]); h0.w = f2bf(hv[3]);
  h1.x = f2bf(hv[4]); h1.y = f2bf(hv[5]); h1.z = f2bf(hv[6]); h1.w = f2bf(hv[7]);
  ((ushort4*)(h + (size_t)t * DDIM))[tid * 2]     = h0;
  ((ushort4*)(h + (size_t)t * DDIM))[tid * 2 + 1] = h1;

  float lp[8] = {0, 0, 0, 0, 0, 0, 0, 0};
  const float* rwm = router_w + (size_t)tid * 8 * NEXP;
  #pragma unroll
  for (int j = 0; j < 8; j++) {
    float4 a = ((const float4*)(rwm + j * NEXP))[0];
    float4 b = ((const float4*)(rwm + j * NEXP))[1];
    float hj = hv[j];
    lp[0] += hj * a.x; lp[1] += hj * a.y; lp[2] += hj * a.z; lp[3] += hj * a.w;
    lp[4] += hj * b.x; lp[5] += hj * b.y; lp[6] += hj * b.z; lp[7] += hj * b.w;
  }
  #pragma unroll
  for (int m = 32; m >= 1; m >>= 1) {
    #pragma unroll
    for (int e = 0; e < 8; e++) lp[e] += __shfl_xor(lp[e], m, 64);
  }
  __shared__ float rl[4][8];
  if (lane == 0) {
    #pragma unroll
    for (int e = 0; e < 8; e++) rl[wv][e] = lp[e];
  }
  __syncthreads();
  if (tid == 0) {
    float lg[8];
    #pragma unroll
    for (int e = 0; e < 8; e++) lg[e] = rl[0][e] + rl[1][e] + rl[2][e] + rl[3][e];
    int i0 = 0;
    for (int e = 1; e < 8; e++) if (lg[e] > lg[i0]) i0 = e;   // earliest max
    int i1 = (i0 == 0) ? 1 : 0;
    for (int e = 0; e < 8; e++) if (e != i0 && lg[e] > lg[i1]) i1 = e;
    float p0 = 1.f / (1.f + expf(lg[i1] - lg[i0]));  // renormalized top-2
    topi[t * 2] = i0; topi[t * 2 + 1] = i1;
    topw[t * 2] = p0; topw[t * 2 + 1] = 1.f - p0;
    atomicAdd(&counts[i0], 1);
    atomicAdd(&counts[i1], 1);
  }
}

// ---------------------------------------------------------------------------
__global__ void k_offsets(const int* __restrict__ counts, int* __restrict__ off) {
  if (threadIdx.x == 0 && blockIdx.x == 0) {
    int o = 0;
    for (int e = 0; e < NEXP; e++) { off[e] = o; o += (counts[e] + 127) & ~127; }
    off[8] = o;
    off[9] = o + T_TOK;
  }
}

// ---------------------------------------------------------------------------
__global__ __launch_bounds__(256) void k_scatter(
    const int* __restrict__ topi, const float* __restrict__ topw,
    const int* __restrict__ off, int* __restrict__ cursor,
    int* __restrict__ tokslot, float* __restrict__ wtrow)
{
  int idx = blockIdx.x * 256 + threadIdx.x;   // 0..24575
  if (idx < T_TOK * 2) {
    int t = idx >> 1, k = idx & 1;
    int e = topi[idx];
    int slot = atomicAdd(&cursor[e], 1);
    int row = off[e] + slot;
    tokslot[row] = t * 4 + k;
    wtrow[row] = topw[idx];
  } else {
    int t = idx - T_TOK * 2;
    int row = off[8] + t;
    tokslot[row] = t * 4 + 2;
    wtrow[row] = 1.0f;
  }
}

// ---------------------------------------------------------------------------
// K4a: batched convert-transpose for D->F weights ([2048][1024] -> [1024][2048]):
//   z 0..7 = wg experts, 8..15 = wu experts, 16 = sg, 17 = su.
// ---------------------------------------------------------------------------
__global__ __launch_bounds__(256) void k_tr_df(
    const float* __restrict__ wg, const float* __restrict__ wu,
    const float* __restrict__ sg, const float* __restrict__ su,
    uint16_t* __restrict__ wgT, uint16_t* __restrict__ wuT,
    uint16_t* __restrict__ sgT, uint16_t* __restrict__ suT)
{
  __shared__ float tile[32][33];
  int z = blockIdx.z;
  const float* src; uint16_t* dst;
  if (z < 8)       { src = wg + (size_t)z * DDIM * FDIM;       dst = wgT + (size_t)z * FDIM * DDIM; }
  else if (z < 16) { src = wu + (size_t)(z - 8) * DDIM * FDIM; dst = wuT + (size_t)(z - 8) * FDIM * DDIM; }
  else if (z == 16){ src = sg; dst = sgT; }
  else             { src = su; dst = suT; }
  int c0 = blockIdx.x * 32, r0 = blockIdx.y * 32;
  int tx = threadIdx.x & 31, ty = threadIdx.x >> 5;  // 32x8
  #pragma unroll
  for (int i = 0; i < 4; i++)
    tile[ty + 8 * i][tx] = src[(size_t)(r0 + ty + 8 * i) * FDIM + c0 + tx];
  __syncthreads();
  #pragma unroll
  for (int i = 0; i < 4; i++)
    dst[(size_t)(c0 + ty + 8 * i) * DDIM + r0 + tx] = f2bf(tile[tx][ty + 8 * i]);
}

// K4b: batched convert-transpose for F->D weights ([1024][2048] -> [2048][1024]):
//   z 0..7 = wd experts, 8 = sd.
__global__ __launch_bounds__(256) void k_tr_fd(
    const float* __restrict__ wd, const float* __restrict__ sd,
    uint16_t* __restrict__ wdT, uint16_t* __restrict__ sdT)
{
  __shared__ float tile[32][33];
  int z = blockIdx.z;
  const float* src; uint16_t* dst;
  if (z < 8) { src = wd + (size_t)z * FDIM * DDIM; dst = wdT + (size_t)z * DDIM * FDIM; }
  else       { src = sd; dst = sdT; }
  int c0 = blockIdx.x * 32, r0 = blockIdx.y * 32;
  int tx = threadIdx.x & 31, ty = threadIdx.x >> 5;  // 32x8
  #pragma unroll
  for (int i = 0; i < 4; i++)
    tile[ty + 8 * i][tx] = src[(size_t)(r0 + ty + 8 * i) * DDIM + c0 + tx];
  __syncthreads();
  #pragma unroll
  for (int i = 0; i < 4; i++)
    dst[(size_t)(c0 + ty + 8 * i) * FDIM + r0 + tx] = f2bf(tile[tx][ty + 8 * i]);
}

// ---------------------------------------------------------------------------
// K5: stage-1 grouped GEMM, 128x128 tile via concat-B (rows 0..63 = W_gate,
// 64..127 = W_up). gload_lds w16 staging, pre-swizzled source + XOR read (T2).
// GRID: x = f-tile (FAST, 16) for cross-block A-tile L2 reuse; y = row-tile.
// ---------------------------------------------------------------------------
__global__ __launch_bounds__(256) void k_stage1(
    const uint16_t* __restrict__ h, const uint16_t* __restrict__ wgT,
    const uint16_t* __restrict__ wuT, const uint16_t* __restrict__ sgT,
    const uint16_t* __restrict__ suT, const int* __restrict__ off,
    const int* __restrict__ tokslot, uint16_t* __restrict__ A_int)
{
  __shared__ __align__(16) uint16_t sAB[2 * 128 * 64];  // 32 KB; reused as fp32 uBuf
  uint16_t* sA = sAB;
  uint16_t* sB = sAB + 128 * 64;

  int row0 = blockIdx.y * 128;           // row-tile = SLOW grid dim
  int end = off[9];
  if (row0 >= end) return;
  int e = 0;
  #pragma unroll 1
  for (; e < 9; e++) if (row0 >= off[e] && row0 < off[e + 1]) break;
  const uint16_t* bg = (e < NEXP) ? wgT + (size_t)e * FDIM * DDIM : sgT;
  const uint16_t* bu = (e < NEXP) ? wuT + (size_t)e * FDIM * DDIM : suT;
  int f0 = blockIdx.x * 64;              // f-tile = FAST grid dim

  int tid = threadIdx.x, lane = tid & 63, w = tid >> 6;

  // staging: granule G = w*256+i*64+lane -> LDS row r=G>>3, phys slot sl=G&7.
  // source granule gl = sl ^ (r&7) (pre-swizzle so read-side XOR restores).
  const uint16_t* srcA[4];
  const uint16_t* srcB[4];
  #pragma unroll
  for (int i = 0; i < 4; i++) {
    int r = w * 32 + i * 8 + (lane >> 3);
    int sl = lane & 7;
    int gl = sl ^ (r & 7);
    int ts = tokslot[row0 + r];
    int tok = ts < 0 ? 0 : (ts >> 2);       // padded rows: token 0 (discarded)
    srcA[i] = h + (size_t)tok * DDIM + gl * 8;
    const uint16_t* bb = (r < 64) ? (bg + (size_t)(f0 + r) * DDIM)
                                  : (bu + (size_t)(f0 + r - 64) * DDIM);
    srcB[i] = bb + gl * 8;
  }

  f32x4 acc[4][4] = {};

  for (int kt = 0; kt < DDIM; kt += BK) {
    #pragma unroll
    for (int i = 0; i < 4; i++) {
      gload16(srcA[i] + kt, sA + (w * 256 + i * 64) * 8);
      gload16(srcB[i] + kt, sB + (w * 256 + i * 64) * 8);
    }
    __syncthreads();
    #pragma unroll
    for (int ks = 0; ks < 2; ks++) {
      int ce = ks * 32 + ((lane >> 4) << 3);   // logical element offset in K-tile
      bf16x8 av[4], bv[4];
      #pragma unroll
      for (int m = 0; m < 4; m++) {
        int rr = (w & 1) * 64 + m * 16 + (lane & 15);
        av[m] = *(const bf16x8*)(sA + rr * 64 + (ce ^ ((rr & 7) << 3)));
      }
      #pragma unroll
      for (int n = 0; n < 4; n++) {
        int rr = (w >> 1) * 64 + n * 16 + (lane & 15);
        bv[n] = *(const bf16x8*)(sB + rr * 64 + (ce ^ ((rr & 7) << 3)));
      }
      #pragma unroll
      for (int m = 0; m < 4; m++) {
        #pragma unroll
        for (int n = 0; n < 4; n++)
          acc[m][n] = __builtin_amdgcn_mfma_f32_16x16x32_bf16(av[m], bv[n], acc[m][n], 0, 0, 0);
      }
    }
    __syncthreads();
  }

  // epilogue: waves 2,3 hold the U-half -> stash fp32 in LDS; waves 0,1 hold G.
  float* uBuf = (float*)sAB;   // [128][64] fp32 = 32 KB
  if (w >= 2) {
    #pragma unroll
    for (int m = 0; m < 4; m++) {
      #pragma unroll
      for (int n = 0; n < 4; n++) {
        #pragma unroll
        for (int r = 0; r < 4; r++) {
          int lrow = (w & 1) * 64 + m * 16 + ((lane >> 4) << 2) + r;
          int col = n * 16 + (lane & 15);
          uBuf[lrow * 64 + col] = acc[m][n][r];
        }
      }
    }
  }
  __syncthreads();
  if (w < 2) {
    #pragma unroll
    for (int m = 0; m < 4; m++) {
      #pragma unroll
      for (int n = 0; n < 4; n++) {
        #pragma unroll
        for (int r = 0; r < 4; r++) {
          int lrow = (w & 1) * 64 + m * 16 + ((lane >> 4) << 2) + r;
          int col = n * 16 + (lane & 15);
          float g = acc[m][n][r];
          float u = uBuf[lrow * 64 + col];
          float a = (g / (1.f + expf(-g))) * u;
          A_int[(size_t)(row0 + lrow) * FDIM + f0 + col] = f2bf(a);
        }
      }
    }
  }
}

// ---------------------------------------------------------------------------
// K6: stage-2 grouped GEMM: EO = A_int @ W_down. Same T2-swizzled staging.
// GRID: x = d-tile (FAST, 16) for cross-block A-tile L2 reuse; y = row-tile.
// Routed rows: fp32*weight -> eo_r[tok][slot][*]. Shared rows: fp32 -> out.
// ---------------------------------------------------------------------------
__global__ __launch_bounds__(256) void k_stage2(
    const uint16_t* __restrict__ A_int, const uint16_t* __restrict__ wdT,
    const uint16_t* __restrict__ sdT, const int* __restrict__ off,
    const int* __restrict__ tokslot, const float* __restrict__ wtrow,
    float* __restrict__ eo_r, float* __restrict__ out)
{
  __shared__ __align__(16) uint16_t sA[128 * 64];
  __shared__ __align__(16) uint16_t sB[128 * 64];

  int row0 = blockIdx.y * 128;           // row-tile = SLOW grid dim
  int end = off[9];
  if (row0 >= end) return;
  int e = 0;
  #pragma unroll 1
  for (; e < 9; e++) if (row0 >= off[e] && row0 < off[e + 1]) break;
  const uint16_t* bw = (e < NEXP) ? wdT + (size_t)e * DDIM * FDIM : sdT;
  int d0 = blockIdx.x * 128;             // d-tile = FAST grid dim

  int tid = threadIdx.x, lane = tid & 63, w = tid >> 6;

  const uint16_t* srcA[4];
  const uint16_t* srcB[4];
  #pragma unroll
  for (int i = 0; i < 4; i++) {
    int r = w * 32 + i * 8 + (lane >> 3);
    int sl = lane & 7;
    int gl = sl ^ (r & 7);
    srcA[i] = A_int + (size_t)(row0 + r) * FDIM + gl * 8;
    srcB[i] = bw + (size_t)(d0 + r) * FDIM + gl * 8;
  }

  f32x4 acc[4][4] = {};

  for (int kt = 0; kt < FDIM; kt += BK) {
    #pragma unroll
    for (int i = 0; i < 4; i++) {
      gload16(srcA[i] + kt, sA + (w * 256 + i * 64) * 8);
      gload16(srcB[i] + kt, sB + (w * 256 + i * 64) * 8);
    }
    __syncthreads();
    #pragma unroll
    for (int ks = 0; ks < 2; ks++) {
      int ce = ks * 32 + ((lane >> 4) << 3);
      bf16x8 av[4], bv[4];
      #pragma unroll
      for (int m = 0; m < 4; m++) {
        int rr = (w & 1) * 64 + m * 16 + (lane & 15);
        av[m] = *(const bf16x8*)(sA + rr * 64 + (ce ^ ((rr & 7) << 3)));
      }
      #pragma unroll
      for (int n = 0; n < 4; n++) {
        int rr = (w >> 1) * 64 + n * 16 + (lane & 15);
        bv[n] = *(const bf16x8*)(sB + rr * 64 + (ce ^ ((rr & 7) << 3)));
      }
      #pragma unroll
      for (int m = 0; m < 4; m++) {
        #pragma unroll
        for (int n = 0; n < 4; n++)
          acc[m][n] = __builtin_amdgcn_mfma_f32_16x16x32_bf16(av[m], bv[n], acc[m][n], 0, 0, 0);
      }
    }
    __syncthreads();
  }

  int wr = (w & 1) * 64, wc = (w >> 1) * 64;
  #pragma unroll
  for (int m = 0; m < 4; m++) {
    #pragma unroll
    for (int r = 0; r < 4; r++) {
      int grow = row0 + wr + m * 16 + ((lane >> 4) << 2) + r;
      int ts = tokslot[grow];
      if (ts < 0) continue;                  // padded row
      int tok = ts >> 2, slot = ts & 3;
      if (slot == 2) {                       // shared expert -> fp32 out
        size_t obase = (size_t)tok * DDIM;
        #pragma unroll
        for (int n = 0; n < 4; n++) {
          int col = d0 + wc + n * 16 + (lane & 15);
          out[obase + col] = acc[m][n][r];
        }
      } else {                               // routed -> fp32 weighted slot
        float wt = wtrow[grow];
        size_t obase = ((size_t)tok * 2 + slot) * DDIM;
        #pragma unroll
        for (int n = 0; n < 4; n++) {
          int col = d0 + wc + n * 16 + (lane & 15);
          eo_r[obase + col] = acc[m][n][r] * wt;
        }
      }
    }
  }
}

// ---------------------------------------------------------------------------
// K7: out = out_shared + eo_r[slot0] + eo_r[slot1]   (all fp32)
// ---------------------------------------------------------------------------
__global__ __launch_bounds__(256) void k_final(
    const float* __restrict__ eo_r, float* __restrict__ out)
{
  int tok = blockIdx.x;
  int col = threadIdx.x * 8;
  const float* e0 = eo_r + ((size_t)tok * 2) * DDIM + col;
  const float* e1 = eo_r + ((size_t)tok * 2 + 1) * DDIM + col;
  float* op = out + (size_t)tok * DDIM + col;
  float4 s0 = *(const float4*)(op);
  float4 s1 = *(const float4*)(op + 4);
  float4 a0 = *(const float4*)(e0);
  float4 a1 = *(const float4*)(e0 + 4);
  float4 b0 = *(const float4*)(e1);
  float4 b1 = *(const float4*)(e1 + 4);
  float4 o0, o1;
  o0.x = s0.x + a0.x + b0.x;  o0.y = s0.y + a0.y + b0.y;
  o0.z = s0.z + a0.z + b0.z;  o0.w = s0.w + a0.w + b0.w;
  o1.x = s1.x + a1.x + b1.x;  o1.y = s1.y + a1.y + b1.y;
  o1.z = s1.z + a1.z + b1.z;  o1.w = s1.w + a1.w + b1.w;
  *(float4*)(op) = o0;
  *(float4*)(op + 4) = o1;
}

// ---------------------------------------------------------------------------
extern "C" void kernel_launch(void* const* d_in, const int* in_sizes, int n_in,
                              void* d_out, int out_size, void* d_ws, size_t ws_size,
                              hipStream_t stream) {
  (void)in_sizes; (void)n_in; (void)out_size;
  const float* x    = (const float*)d_in[0];
  const float* rmsw = (const float*)d_in[1];
  const float* rtw  = (const float*)d_in[2];
  const float* wg   = (const float*)d_in[3];
  const float* wu   = (const float*)d_in[4];
  const float* wd   = (const float*)d_in[5];
  const float* sg   = (const float*)d_in[6];
  const float* su   = (const float*)d_in[7];
  const float* sd   = (const float*)d_in[8];
  float* out = (float*)d_out;   // reference output dtype is float32

  // ---- workspace layout with lifetime overlays (224.73 MB, known to fit) ----
  char* base = (char*)d_ws;
  size_t off_b = 0;
  auto place = [&](size_t bytes) { size_t r = off_b; off_b += (bytes + 255) & ~(size_t)255; return r; };
  size_t o_topi    = place((size_t)T_TOK * 2 * 4);
  size_t o_topw    = place((size_t)T_TOK * 2 * 4);
  size_t o_counts  = place(64);
  size_t o_offs    = place(64);
  size_t o_cursor  = place(64);
  size_t o_tokslot = place((size_t)CAP * 4);
  size_t o_wtrow   = place((size_t)CAP * 4);
  // eo_r: fp32 [T][2][D] (phase C/D). Overlaid by h/wgT/wuT/sgT/suT (phase A/B).
  size_t o_eor = place((size_t)T_TOK * 2 * DDIM * 4);           // 134.22 MB
  size_t o_h   = o_eor;                                         // 33.55 MB
  size_t o_wgT = o_eor + (size_t)T_TOK * DDIM * 2;              // 33.55 MB
  size_t o_wuT = o_wgT + (size_t)NEXP * FDIM * DDIM * 2;        // 33.55 MB
  size_t o_sgT = o_wuT + (size_t)NEXP * FDIM * DDIM * 2;        // 4.19 MB
  size_t o_suT = o_sgT + (size_t)FDIM * DDIM * 2;               // 4.19 MB (ends 109.05 < 134.22)
  size_t o_wdT = place((size_t)NEXP * DDIM * FDIM * 2);         // 33.55 MB
  size_t o_sdT = place((size_t)DDIM * FDIM * 2);                // 4.19 MB
  size_t o_Ai  = place((size_t)CAP * FDIM * 2);                 // 52.43 MB
  size_t NEED = off_b;
  if (ws_size < NEED) return;  // clean diagnostic instead of fault

  int*      topi    = (int*)(base + o_topi);
  float*    topw    = (float*)(base + o_topw);
  int*      counts  = (int*)(base + o_counts);
  int*      offs    = (int*)(base + o_offs);
  int*      cursor  = (int*)(base + o_cursor);
  int*      tokslot = (int*)(base + o_tokslot);
  float*    wtrow   = (float*)(base + o_wtrow);
  float*    eo_r    = (float*)(base + o_eor);
  uint16_t* h       = (uint16_t*)(base + o_h);
  uint16_t* wgT     = (uint16_t*)(base + o_wgT);
  uint16_t* wuT     = (uint16_t*)(base + o_wuT);
  uint16_t* sgT     = (uint16_t*)(base + o_sgT);
  uint16_t* suT     = (uint16_t*)(base + o_suT);
  uint16_t* wdT     = (uint16_t*)(base + o_wdT);
  uint16_t* sdT     = (uint16_t*)(base + o_sdT);
  uint16_t* Ai      = (uint16_t*)(base + o_Ai);

  hipMemsetAsync(counts, 0, 64, stream);
  hipMemsetAsync(cursor, 0, 64, stream);
  hipMemsetAsync(tokslot, 0xFF, (size_t)CAP * 4, stream);  // -1 = padded row

  // batched fp32 -> bf16 convert-transposes (2 launches)
  k_tr_df<<<dim3(FDIM / 32, DDIM / 32, 18), 256, 0, stream>>>(wg, wu, sg, su, wgT, wuT, sgT, suT);
  k_tr_fd<<<dim3(DDIM / 32, FDIM / 32, 9),  256, 0, stream>>>(wd, sd, wdT, sdT);

  k_rms_router<<<T_TOK, 256, 0, stream>>>(x, rmsw, rtw, h, topi, topw, counts);
  k_offsets<<<1, 64, 0, stream>>>(counts, offs);
  k_scatter<<<(T_TOK * 3) / 256, 256, 0, stream>>>(topi, topw, offs, cursor, tokslot, wtrow);

  // f/d-tile fastest (x), row-tile slow (y): cross-block A-tile L2 reuse
  k_stage1<<<dim3(FDIM / 64, NT_M), 256, 0, stream>>>(h, wgT, wuT, sgT, suT, offs, tokslot, Ai);
  // stage2 overwrites the h/wgT/wuT/sgT/suT region (now dead) as eo_r
  k_stage2<<<dim3(DDIM / 128, NT_M), 256, 0, stream>>>(Ai, wdT, sdT, offs, tokslot, wtrow, eo_r, out);
  k_final<<<T_TOK, 256, 0, stream>>>(eo_r, out);
}

// Round 11
// 745.765 us; speedup vs baseline: 1.2667x; 1.1632x over previous
//
#include <hip/hip_runtime.h>
#include <stdint.h>

// Problem constants (B=4,S=2048 -> T=8192 tokens). Inputs fp32, OUTPUT fp32.
#define T_TOK 8192
#define DDIM  2048
#define NEXP  8
#define FDIM  1024
#define CAP   25600   // 16384 assignments + 8*128 pad + 8192 shared rows
#define NT_M  200     // CAP/128 M-tiles
#define BK    64

typedef __bf16 bf16x8 __attribute__((ext_vector_type(8)));
typedef float  f32x4  __attribute__((ext_vector_type(4)));

typedef const __attribute__((address_space(1))) uint32_t* as1_u32;
typedef __attribute__((address_space(3))) uint32_t* as3_u32;

__device__ __forceinline__ void gload16(const void* g, void* l) {
  __builtin_amdgcn_global_load_lds((as1_u32)g, (as3_u32)l, 16, 0, 0);
}
__device__ __forceinline__ float bf2f(uint16_t u) {
  union { uint32_t i; float f; } v; v.i = ((uint32_t)u) << 16; return v.f;
}
__device__ __forceinline__ uint16_t f2bf(float f) {
  union { float f; uint32_t i; } v; v.f = f;
  uint32_t i = v.i;
  i += 0x7FFFu + ((i >> 16) & 1u);   // RNE
  return (uint16_t)(i >> 16);
}

// ---------------------------------------------------------------------------
// K1: RMSNorm + router (unchanged, proven).
// ---------------------------------------------------------------------------
__global__ __launch_bounds__(256) void k_rms_router(
    const float* __restrict__ x, const float* __restrict__ rmsw,
    const float* __restrict__ router_w, uint16_t* __restrict__ h,
    int* __restrict__ topi, float* __restrict__ topw, int* __restrict__ counts)
{
  int t = blockIdx.x, tid = threadIdx.x;
  int lane = tid & 63, wv = tid >> 6;
  const float* xr = x + (size_t)t * DDIM;
  float4 x0 = ((const float4*)xr)[tid * 2];
  float4 x1 = ((const float4*)xr)[tid * 2 + 1];
  float4 w0 = ((const float4*)rmsw)[tid * 2];
  float4 w1 = ((const float4*)rmsw)[tid * 2 + 1];
  float xv[8] = {x0.x, x0.y, x0.z, x0.w, x1.x, x1.y, x1.z, x1.w};
  float wv8[8] = {w0.x, w0.y, w0.z, w0.w, w1.x, w1.y, w1.z, w1.w};
  float ss = 0.f;
  #pragma unroll
  for (int j = 0; j < 8; j++) ss += xv[j] * xv[j];
  #pragma unroll
  for (int m = 32; m >= 1; m >>= 1) ss += __shfl_xor(ss, m, 64);
  __shared__ float rs[4];
  __shared__ float sscale;
  if (lane == 0) rs[wv] = ss;
  __syncthreads();
  if (tid == 0) sscale = rsqrtf((rs[0] + rs[1] + rs[2] + rs[3]) * (1.0f / DDIM) + 1e-6f);
  __syncthreads();
  float scale = sscale;
  float hv[8];
  #pragma unroll
  for (int j = 0; j < 8; j++) hv[j] = xv[j] * scale * wv8[j];
  ushort4 h0, h1;
  h0.x = f2bf(hv[0]); h0.y = f2bf(hv[1]); h0.z = f2bf(hv[2]); h0.w = f2bf(hv[3]);
  h1.x = f2bf(hv[4]); h1.y = f2bf(hv[5]); h1.z = f2bf(hv[6]); h1.w = f2bf(hv[7]);
  ((ushort4*)(h + (size_t)t * DDIM))[tid * 2]     = h0;
  ((ushort4*)(h + (size_t)t * DDIM))[tid * 2 + 1] = h1;

  float lp[8] = {0, 0, 0, 0, 0, 0, 0, 0};
  const float* rwm = router_w + (size_t)tid * 8 * NEXP;
  #pragma unroll
  for (int j = 0; j < 8; j++) {
    float4 a = ((const float4*)(rwm + j * NEXP))[0];
    float4 b = ((const float4*)(rwm + j * NEXP))[1];
    float hj = hv[j];
    lp[0] += hj * a.x; lp[1] += hj * a.y; lp[2] += hj * a.z; lp[3] += hj * a.w;
    lp[4] += hj * b.x; lp[5] += hj * b.y; lp[6] += hj * b.z; lp[7] += hj * b.w;
  }
  #pragma unroll
  for (int m = 32; m >= 1; m >>= 1) {
    #pragma unroll
    for (int e = 0; e < 8; e++) lp[e] += __shfl_xor(lp[e], m, 64);
  }
  __shared__ float rl[4][8];
  if (lane == 0) {
    #pragma unroll
    for (int e = 0; e < 8; e++) rl[wv][e] = lp[e];
  }
  __syncthreads();
  if (tid == 0) {
    float lg[8];
    #pragma unroll
    for (int e = 0; e < 8; e++) lg[e] = rl[0][e] + rl[1][e] + rl[2][e] + rl[3][e];
    int i0 = 0;
    for (int e = 1; e < 8; e++) if (lg[e] > lg[i0]) i0 = e;   // earliest max
    int i1 = (i0 == 0) ? 1 : 0;
    for (int e = 0; e < 8; e++) if (e != i0 && lg[e] > lg[i1]) i1 = e;
    float p0 = 1.f / (1.f + expf(lg[i1] - lg[i0]));
    topi[t * 2] = i0; topi[t * 2 + 1] = i1;
    topw[t * 2] = p0; topw[t * 2 + 1] = 1.f - p0;
    atomicAdd(&counts[i0], 1);
    atomicAdd(&counts[i1], 1);
  }
}

// ---------------------------------------------------------------------------
__global__ void k_offsets(const int* __restrict__ counts, int* __restrict__ off) {
  if (threadIdx.x == 0 && blockIdx.x == 0) {
    int o = 0;
    for (int e = 0; e < NEXP; e++) { off[e] = o; o += (counts[e] + 127) & ~127; }
    off[8] = o;
    off[9] = o + T_TOK;
  }
}

// ---------------------------------------------------------------------------
__global__ __launch_bounds__(256) void k_scatter(
    const int* __restrict__ topi, const float* __restrict__ topw,
    const int* __restrict__ off, int* __restrict__ cursor,
    int* __restrict__ tokslot, float* __restrict__ wtrow)
{
  int idx = blockIdx.x * 256 + threadIdx.x;   // 0..24575
  if (idx < T_TOK * 2) {
    int t = idx >> 1, k = idx & 1;
    int e = topi[idx];
    int slot = atomicAdd(&cursor[e], 1);
    int row = off[e] + slot;
    tokslot[row] = t * 4 + k;
    wtrow[row] = topw[idx];
  } else {
    int t = idx - T_TOK * 2;
    int row = off[8] + t;
    tokslot[row] = t * 4 + 2;
    wtrow[row] = 1.0f;
  }
}

// ---------------------------------------------------------------------------
// K4a/K4b: batched convert-transposes (unchanged).
// ---------------------------------------------------------------------------
__global__ __launch_bounds__(256) void k_tr_df(
    const float* __restrict__ wg, const float* __restrict__ wu,
    const float* __restrict__ sg, const float* __restrict__ su,
    uint16_t* __restrict__ wgT, uint16_t* __restrict__ wuT,
    uint16_t* __restrict__ sgT, uint16_t* __restrict__ suT)
{
  __shared__ float tile[32][33];
  int z = blockIdx.z;
  const float* src; uint16_t* dst;
  if (z < 8)       { src = wg + (size_t)z * DDIM * FDIM;       dst = wgT + (size_t)z * FDIM * DDIM; }
  else if (z < 16) { src = wu + (size_t)(z - 8) * DDIM * FDIM; dst = wuT + (size_t)(z - 8) * FDIM * DDIM; }
  else if (z == 16){ src = sg; dst = sgT; }
  else             { src = su; dst = suT; }
  int c0 = blockIdx.x * 32, r0 = blockIdx.y * 32;
  int tx = threadIdx.x & 31, ty = threadIdx.x >> 5;
  #pragma unroll
  for (int i = 0; i < 4; i++)
    tile[ty + 8 * i][tx] = src[(size_t)(r0 + ty + 8 * i) * FDIM + c0 + tx];
  __syncthreads();
  #pragma unroll
  for (int i = 0; i < 4; i++)
    dst[(size_t)(c0 + ty + 8 * i) * DDIM + r0 + tx] = f2bf(tile[tx][ty + 8 * i]);
}

__global__ __launch_bounds__(256) void k_tr_fd(
    const float* __restrict__ wd, const float* __restrict__ sd,
    uint16_t* __restrict__ wdT, uint16_t* __restrict__ sdT)
{
  __shared__ float tile[32][33];
  int z = blockIdx.z;
  const float* src; uint16_t* dst;
  if (z < 8) { src = wd + (size_t)z * FDIM * DDIM; dst = wdT + (size_t)z * DDIM * FDIM; }
  else       { src = sd; dst = sdT; }
  int c0 = blockIdx.x * 32, r0 = blockIdx.y * 32;
  int tx = threadIdx.x & 31, ty = threadIdx.x >> 5;
  #pragma unroll
  for (int i = 0; i < 4; i++)
    tile[ty + 8 * i][tx] = src[(size_t)(r0 + ty + 8 * i) * DDIM + c0 + tx];
  __syncthreads();
  #pragma unroll
  for (int i = 0; i < 4; i++)
    dst[(size_t)(c0 + ty + 8 * i) * FDIM + r0 + tx] = f2bf(tile[tx][ty + 8 * i]);
}

// ---------------------------------------------------------------------------
// Shared GEMM machinery: 128x128 tile, BK=64, 4 waves (2x2), DOUBLE-buffered
// 64KB LDS. Per K-tile: stage t+1 -> other buffer (safe: disjoint), compute
// tile t barrier-free, ONE __syncthreads() (vmcnt0+lgkm0+barrier) per tile.
// T2 swizzle: source granule gl = sl ^ (r&7); read XOR (ce ^ ((rr&7)<<3)).
// ---------------------------------------------------------------------------
// LDS elems: A0 [0,8192) B0 [8192,16384) A1 [16384,24576) B1 [24576,32768)
#define BUFA(c) (ldsu + (size_t)(c) * 16384)
#define BUFB(c) (ldsu + 8192 + (size_t)(c) * 16384)

#define STAGE8(T, C) do {                                                     \
  _Pragma("unroll") for (int i_ = 0; i_ < 4; i_++) {                          \
    int G_ = w * 256 + i_ * 64 + lane;                                        \
    gload16(aSrc[i_] + (size_t)(T) * BK, BUFA(C) + G_ * 8);                   \
    gload16(bSrc[i_] + (size_t)(T) * BK, BUFB(C) + G_ * 8);                   \
  } } while (0)

#define COMPUTE_TILE(curA, curB) do {                                         \
  _Pragma("unroll") for (int ks_ = 0; ks_ < 2; ks_++) {                       \
    int ce_ = ks_ * 32 + ((lane >> 4) << 3);                                  \
    bf16x8 av_[4], bv_[4];                                                    \
    _Pragma("unroll") for (int m_ = 0; m_ < 4; m_++) {                        \
      int rr_ = wr * 64 + m_ * 16 + (lane & 15);                              \
      av_[m_] = *(const bf16x8*)((curA) + rr_ * 64 + (ce_ ^ ((rr_ & 7) << 3))); \
    }                                                                         \
    _Pragma("unroll") for (int n_ = 0; n_ < 4; n_++) {                        \
      int rr_ = wc * 64 + n_ * 16 + (lane & 15);                              \
      bv_[n_] = *(const bf16x8*)((curB) + rr_ * 64 + (ce_ ^ ((rr_ & 7) << 3))); \
    }                                                                         \
    __builtin_amdgcn_s_setprio(1);                                            \
    _Pragma("unroll") for (int m_ = 0; m_ < 4; m_++)                          \
    _Pragma("unroll") for (int n_ = 0; n_ < 4; n_++)                          \
      acc[m_][n_] = __builtin_amdgcn_mfma_f32_16x16x32_bf16(av_[m_], bv_[n_], acc[m_][n_], 0, 0, 0); \
    __builtin_amdgcn_s_setprio(0);                                            \
  } } while (0)

// ---------------------------------------------------------------------------
// K5: stage-1 grouped GEMM. B-tile rows interleave gate/up in 16-row blocks:
// r -> b=r>>4; type=b&1 (0=gate,1=up); fcol = f0 + (b>>1)*16 + (r&15).
// So wave wc holds acc[m][2p]=gate, acc[m][2p+1]=up for the SAME columns ->
// silu pairing is wave-local, no LDS exchange.
// ---------------------------------------------------------------------------
__global__ __launch_bounds__(256, 2) void k_stage1(
    const uint16_t* __restrict__ h, const uint16_t* __restrict__ wgT,
    const uint16_t* __restrict__ wuT, const uint16_t* __restrict__ sgT,
    const uint16_t* __restrict__ suT, const int* __restrict__ off,
    const int* __restrict__ tokslot, uint16_t* __restrict__ A_int)
{
  __shared__ __align__(16) uint16_t ldsu[32768];   // 64 KB

  int row0 = blockIdx.y * 128;
  int end = off[9];
  if (row0 >= end) return;
  int e = 0;
  #pragma unroll 1
  for (; e < 9; e++) if (row0 >= off[e] && row0 < off[e + 1]) break;
  const uint16_t* bg = (e < NEXP) ? wgT + (size_t)e * FDIM * DDIM : sgT;
  const uint16_t* bu = (e < NEXP) ? wuT + (size_t)e * FDIM * DDIM : suT;
  int f0 = blockIdx.x * 64;   // 64 f-cols per block (gate+up pairs)

  int tid = threadIdx.x, lane = tid & 63, w = tid >> 6;
  int wr = w & 1, wc = w >> 1;

  const uint16_t* aSrc[4];
  const uint16_t* bSrc[4];
  #pragma unroll
  for (int i = 0; i < 4; i++) {
    int G = w * 256 + i * 64 + lane;
    int r = G >> 3, sl = G & 7;
    int gl = sl ^ (r & 7);
    int ts = tokslot[row0 + r];
    int tok = ts < 0 ? 0 : (ts >> 2);
    aSrc[i] = h + (size_t)tok * DDIM + gl * 8;
    int b = r >> 4;
    int fc = f0 + ((b >> 1) << 4) + (r & 15);
    const uint16_t* wbase = (b & 1) ? bu : bg;
    bSrc[i] = wbase + (size_t)fc * DDIM + gl * 8;
  }

  f32x4 acc[4][4] = {};
  const int NT = DDIM / BK;   // 32

  STAGE8(0, 0);
  __syncthreads();

  #pragma unroll 1
  for (int t = 0; t < NT; ++t) {
    int cur = t & 1;
    if (t + 1 < NT) STAGE8(t + 1, cur ^ 1);
    const uint16_t* curA = BUFA(cur);
    const uint16_t* curB = BUFB(cur);
    COMPUTE_TILE(curA, curB);
    __syncthreads();   // drains vmcnt (t+1 staged) + barrier
  }

  // epilogue: pairs are wave-local (acc[m][2p]=gate, acc[m][2p+1]=up)
  #pragma unroll
  for (int m = 0; m < 4; m++) {
    #pragma unroll
    for (int p = 0; p < 2; p++) {
      #pragma unroll
      for (int r = 0; r < 4; r++) {
        int row = row0 + wr * 64 + m * 16 + ((lane >> 4) << 2) + r;
        int col = f0 + wc * 32 + p * 16 + (lane & 15);
        float g = acc[m][2 * p][r];
        float u = acc[m][2 * p + 1][r];
        float a = (g / (1.f + expf(-g))) * u;
        A_int[(size_t)row * FDIM + col] = f2bf(a);
      }
    }
  }
}

// ---------------------------------------------------------------------------
// K6: stage-2 grouped GEMM: EO = A_int @ W_down. Same pipelined core.
// Routed rows: bf16*weight -> eo[tok][slot][*]. Shared rows: fp32 -> out.
// ---------------------------------------------------------------------------
__global__ __launch_bounds__(256, 2) void k_stage2(
    const uint16_t* __restrict__ A_int, const uint16_t* __restrict__ wdT,
    const uint16_t* __restrict__ sdT, const int* __restrict__ off,
    const int* __restrict__ tokslot, const float* __restrict__ wtrow,
    uint16_t* __restrict__ eo, float* __restrict__ out)
{
  __shared__ __align__(16) uint16_t ldsu[32768];   // 64 KB

  int row0 = blockIdx.y * 128;
  int end = off[9];
  if (row0 >= end) return;
  int e = 0;
  #pragma unroll 1
  for (; e < 9; e++) if (row0 >= off[e] && row0 < off[e + 1]) break;
  const uint16_t* bw = (e < NEXP) ? wdT + (size_t)e * DDIM * FDIM : sdT;
  int d0 = blockIdx.x * 128;

  int tid = threadIdx.x, lane = tid & 63, w = tid >> 6;
  int wr = w & 1, wc = w >> 1;

  const uint16_t* aSrc[4];
  const uint16_t* bSrc[4];
  #pragma unroll
  for (int i = 0; i < 4; i++) {
    int G = w * 256 + i * 64 + lane;
    int r = G >> 3, sl = G & 7;
    int gl = sl ^ (r & 7);
    aSrc[i] = A_int + (size_t)(row0 + r) * FDIM + gl * 8;
    bSrc[i] = bw + (size_t)(d0 + r) * FDIM + gl * 8;
  }

  f32x4 acc[4][4] = {};
  const int NT = FDIM / BK;   // 16

  STAGE8(0, 0);
  __syncthreads();

  #pragma unroll 1
  for (int t = 0; t < NT; ++t) {
    int cur = t & 1;
    if (t + 1 < NT) STAGE8(t + 1, cur ^ 1);
    const uint16_t* curA = BUFA(cur);
    const uint16_t* curB = BUFB(cur);
    COMPUTE_TILE(curA, curB);
    __syncthreads();
  }

  #pragma unroll
  for (int m = 0; m < 4; m++) {
    #pragma unroll
    for (int r = 0; r < 4; r++) {
      int grow = row0 + wr * 64 + m * 16 + ((lane >> 4) << 2) + r;
      int ts = tokslot[grow];
      if (ts < 0) continue;                  // padded row
      int tok = ts >> 2, slot = ts & 3;
      if (slot == 2) {                       // shared expert -> fp32 out
        size_t obase = (size_t)tok * DDIM;
        #pragma unroll
        for (int n = 0; n < 4; n++) {
          int col = d0 + wc * 64 + n * 16 + (lane & 15);
          out[obase + col] = acc[m][n][r];
        }
      } else {                               // routed -> bf16 weighted slot
        float wt = wtrow[grow];
        size_t obase = ((size_t)tok * 2 + slot) * DDIM;
        #pragma unroll
        for (int n = 0; n < 4; n++) {
          int col = d0 + wc * 64 + n * 16 + (lane & 15);
          eo[obase + col] = f2bf(acc[m][n][r] * wt);
        }
      }
    }
  }
}

// ---------------------------------------------------------------------------
// K7: out = out_shared(fp32) + eo[slot0](bf16) + eo[slot1](bf16)
// ---------------------------------------------------------------------------
__global__ __launch_bounds__(256) void k_final(
    const uint16_t* __restrict__ eo, float* __restrict__ out)
{
  int tok = blockIdx.x;
  int col = threadIdx.x * 8;
  const uint16_t* e0 = eo + ((size_t)tok * 2) * DDIM + col;
  const uint16_t* e1 = eo + ((size_t)tok * 2 + 1) * DDIM + col;
  float* op = out + (size_t)tok * DDIM + col;
  ushort4 a0 = *(const ushort4*)(e0);
  ushort4 a1 = *(const ushort4*)(e0 + 4);
  ushort4 b0 = *(const ushort4*)(e1);
  ushort4 b1 = *(const ushort4*)(e1 + 4);
  float4 s0 = *(const float4*)(op);
  float4 s1 = *(const float4*)(op + 4);
  float4 o0, o1;
  o0.x = s0.x + bf2f(a0.x) + bf2f(b0.x);
  o0.y = s0.y + bf2f(a0.y) + bf2f(b0.y);
  o0.z = s0.z + bf2f(a0.z) + bf2f(b0.z);
  o0.w = s0.w + bf2f(a0.w) + bf2f(b0.w);
  o1.x = s1.x + bf2f(a1.x) + bf2f(b1.x);
  o1.y = s1.y + bf2f(a1.y) + bf2f(b1.y);
  o1.z = s1.z + bf2f(a1.z) + bf2f(b1.z);
  o1.w = s1.w + bf2f(a1.w) + bf2f(b1.w);
  *(float4*)(op) = o0;
  *(float4*)(op + 4) = o1;
}

// ---------------------------------------------------------------------------
extern "C" void kernel_launch(void* const* d_in, const int* in_sizes, int n_in,
                              void* d_out, int out_size, void* d_ws, size_t ws_size,
                              hipStream_t stream) {
  (void)in_sizes; (void)n_in; (void)out_size;
  const float* x    = (const float*)d_in[0];
  const float* rmsw = (const float*)d_in[1];
  const float* rtw  = (const float*)d_in[2];
  const float* wg   = (const float*)d_in[3];
  const float* wu   = (const float*)d_in[4];
  const float* wd   = (const float*)d_in[5];
  const float* sg   = (const float*)d_in[6];
  const float* su   = (const float*)d_in[7];
  const float* sd   = (const float*)d_in[8];
  float* out = (float*)d_out;

  // ---- workspace layout (~200 MB; known-good budget 224.73 MB) ----
  char* base = (char*)d_ws;
  size_t off_b = 0;
  auto place = [&](size_t bytes) { size_t r = off_b; off_b += (bytes + 255) & ~(size_t)255; return r; };
  size_t o_topi    = place((size_t)T_TOK * 2 * 4);
  size_t o_topw    = place((size_t)T_TOK * 2 * 4);
  size_t o_counts  = place(64);
  size_t o_offs    = place(64);
  size_t o_cursor  = place(64);
  size_t o_tokslot = place((size_t)CAP * 4);
  size_t o_wtrow   = place((size_t)CAP * 4);
  size_t o_h   = place((size_t)T_TOK * DDIM * 2);          // 33.55 MB
  size_t o_wgT = place((size_t)NEXP * FDIM * DDIM * 2);    // 33.55 MB
  size_t o_wuT = place((size_t)NEXP * FDIM * DDIM * 2);    // 33.55 MB
  size_t o_sgT = place((size_t)FDIM * DDIM * 2);           // 4.19 MB
  size_t o_suT = place((size_t)FDIM * DDIM * 2);           // 4.19 MB
  size_t o_wdT = place((size_t)NEXP * DDIM * FDIM * 2);    // 33.55 MB
  size_t o_sdT = place((size_t)DDIM * FDIM * 2);           // 4.19 MB
  size_t o_Ai  = place((size_t)CAP * FDIM * 2);            // 52.43 MB
  // eo (bf16 [T][2][D] = 67.11 MB) overlays h+wgT (both dead after stage1)
  size_t o_eo  = o_h;
  size_t NEED = off_b;
  if (ws_size < NEED) return;

  int*      topi    = (int*)(base + o_topi);
  float*    topw    = (float*)(base + o_topw);
  int*      counts  = (int*)(base + o_counts);
  int*      offs    = (int*)(base + o_offs);
  int*      cursor  = (int*)(base + o_cursor);
  int*      tokslot = (int*)(base + o_tokslot);
  float*    wtrow   = (float*)(base + o_wtrow);
  uint16_t* h       = (uint16_t*)(base + o_h);
  uint16_t* wgT     = (uint16_t*)(base + o_wgT);
  uint16_t* wuT     = (uint16_t*)(base + o_wuT);
  uint16_t* sgT     = (uint16_t*)(base + o_sgT);
  uint16_t* suT     = (uint16_t*)(base + o_suT);
  uint16_t* wdT     = (uint16_t*)(base + o_wdT);
  uint16_t* sdT     = (uint16_t*)(base + o_sdT);
  uint16_t* Ai      = (uint16_t*)(base + o_Ai);
  uint16_t* eo      = (uint16_t*)(base + o_eo);

  hipMemsetAsync(counts, 0, 64, stream);
  hipMemsetAsync(cursor, 0, 64, stream);
  hipMemsetAsync(tokslot, 0xFF, (size_t)CAP * 4, stream);

  k_tr_df<<<dim3(FDIM / 32, DDIM / 32, 18), 256, 0, stream>>>(wg, wu, sg, su, wgT, wuT, sgT, suT);
  k_tr_fd<<<dim3(DDIM / 32, FDIM / 32, 9),  256, 0, stream>>>(wd, sd, wdT, sdT);

  k_rms_router<<<T_TOK, 256, 0, stream>>>(x, rmsw, rtw, h, topi, topw, counts);
  k_offsets<<<1, 64, 0, stream>>>(counts, offs);
  k_scatter<<<(T_TOK * 3) / 256, 256, 0, stream>>>(topi, topw, offs, cursor, tokslot, wtrow);

  // f/d-tile fastest (x) for L2 reuse; row-tile slow (y)
  k_stage1<<<dim3(FDIM / 64, NT_M), 256, 0, stream>>>(h, wgT, wuT, sgT, suT, offs, tokslot, Ai);
  // stage2 overwrites h/wgT (dead) as eo
  k_stage2<<<dim3(DDIM / 128, NT_M), 256, 0, stream>>>(Ai, wdT, sdT, offs, tokslot, wtrow, eo, out);
  k_final<<<T_TOK, 256, 0, stream>>>(eo, out);
}